// Round 5
// baseline (1017.441 us; speedup 1.0000x reference)
//
#include <hip/hip_runtime.h>

#define N_NODES  100000
#define N_EDGES  1600000
#define HIDDEN   128
#define STEPS    4
#define N_GRAPHS 64
#define NBUCK    256
#define BWID     391   // nodes per bucket: 256*391 = 100096 >= 100000
#define GATE_P   136   // gate-buffer row pitch (u16): 16B-aligned rows, bank-staggered

typedef unsigned short u16;
typedef unsigned int   u32;
typedef unsigned long long u64;
typedef __attribute__((ext_vector_type(8))) short bf16x8;
typedef __attribute__((ext_vector_type(4))) float f32x4;

__device__ inline u16 f2bf(float f) {
  u32 u = __float_as_uint(f);
  u = (u + 0x7FFFu + ((u >> 16) & 1u)) >> 16;  // RTNE
  return (u16)u;
}
__device__ inline float bf2f(u16 b) { return __uint_as_float(((u32)b) << 16); }

__device__ inline float fast_sig(float x) { return 1.f / (1.f + __expf(-x)); }
__device__ inline float fast_tanh(float x) {
  x = fminf(fmaxf(x, -15.f), 15.f);
  float e = __expf(2.f * x);
  return (e - 1.f) / (e + 1.f);
}

__device__ inline void gl_lds16(const void* g, void* l) {
  __builtin_amdgcn_global_load_lds((const __attribute__((address_space(1))) void*)g,
                                   (__attribute__((address_space(3))) void*)l, 16, 0, 0);
}

// ---------------- CSR build ----------------
__global__ void k_hist(const int* __restrict__ dst, int* __restrict__ counts) {
  int e = blockIdx.x * 256 + threadIdx.x;
  atomicAdd(&counts[dst[e]], 1);
}

// Hierarchical scan: block-local inclusive scan (98 blocks x 1024).
__global__ void k_scan_blk(const int* __restrict__ counts, int* __restrict__ offs,
                           int* __restrict__ bsum) {
  __shared__ int buf[1024];
  int gid = blockIdx.x * 1024 + threadIdx.x;
  int v = (gid < N_NODES) ? counts[gid] : 0;
  buf[threadIdx.x] = v;
  __syncthreads();
  for (int off = 1; off < 1024; off <<= 1) {
    int t = 0;
    if (threadIdx.x >= off) t = buf[threadIdx.x - off];
    __syncthreads();
    buf[threadIdx.x] += t;
    __syncthreads();
  }
  if (gid < N_NODES) offs[gid] = buf[threadIdx.x];  // inclusive (temp)
  if (threadIdx.x == 1023) bsum[blockIdx.x] = buf[1023];
}

__global__ void k_scan_mid(const int* __restrict__ bsum, int* __restrict__ bbase) {
  __shared__ int buf[128];
  int t = threadIdx.x;
  int v = (t < 98) ? bsum[t] : 0;
  buf[t] = v;
  __syncthreads();
  for (int off = 1; off < 128; off <<= 1) {
    int u = 0;
    if (t >= off) u = buf[t - off];
    __syncthreads();
    buf[t] += u;
    __syncthreads();
  }
  if (t < 98) bbase[t] = buf[t] - v;
}

__global__ void k_scan_fin(const int* __restrict__ counts, int* __restrict__ offs,
                           const int* __restrict__ bbase) {
  int gid = blockIdx.x * 1024 + threadIdx.x;
  if (gid >= N_NODES) return;
  int c = counts[gid];
  int ex = bbase[blockIdx.x] + offs[gid] - c;
  offs[gid] = ex;
  if (gid == N_NODES - 1) offs[N_NODES] = ex + c;
}

// gcursor[b] = csr offset of bucket b's first node.
__global__ void k_binit(const int* __restrict__ offs, int* __restrict__ gcursor) {
  int t = threadIdx.x;
  gcursor[t] = offs[t * BWID];
}

// Pass 1 of multisplit: bucket-grouped append of (dst,src) pairs into ebuf.
__global__ __launch_bounds__(1024) void k_part(const int* __restrict__ esrc,
                                               const int* __restrict__ edst,
                                               int* __restrict__ gcursor,
                                               u64* __restrict__ ebuf) {
  __shared__ int hist[NBUCK];
  __shared__ int base[NBUCK];
  int tid = threadIdx.x;
  if (tid < NBUCK) hist[tid] = 0;
  __syncthreads();
  int e0 = blockIdx.x * 4096;
  int sv[4], dv[4], bk[4], rk[4];
  #pragma unroll
  for (int i = 0; i < 4; ++i) {
    int e = e0 + i * 1024 + tid;
    if (e < N_EDGES) {
      sv[i] = esrc[e];
      dv[i] = edst[e];
      bk[i] = (int)((u32)dv[i] / (u32)BWID);
      rk[i] = atomicAdd(&hist[bk[i]], 1);
    } else bk[i] = -1;
  }
  __syncthreads();
  if (tid < NBUCK) base[tid] = atomicAdd(&gcursor[tid], hist[tid]);
  __syncthreads();
  #pragma unroll
  for (int i = 0; i < 4; ++i) {
    if (bk[i] >= 0) {
      int pos = base[bk[i]] + rk[i];
      ebuf[pos] = ((u64)(u32)dv[i] << 32) | (u32)sv[i];
    }
  }
}

// Pass 2: one bucket per block; LDS per-node cursors; block-exclusive csr region.
__global__ __launch_bounds__(1024) void k_csr(const u64* __restrict__ ebuf,
                                              const int* __restrict__ offs,
                                              int* __restrict__ csr) {
  __shared__ int lcur[BWID];
  int b = blockIdx.x, tid = threadIdx.x;
  int n0 = b * BWID;
  int n1 = min(n0 + BWID, N_NODES);
  int nn = n1 - n0;
  if (tid < nn) lcur[tid] = offs[n0 + tid];
  __syncthreads();
  int e0 = offs[n0], e1 = offs[n1];
  for (int e = e0 + tid; e < e1; e += 1024) {
    u64 p = ebuf[e];
    int src = (int)(p & 0xffffffffull);
    int dst = (int)(p >> 32);
    int pos = atomicAdd(&lcur[dst - n0], 1);
    csr[pos] = src;
  }
}

// ---------------- combined weight build ----------------
// B[256][512] per step, stored fragment-ordered for conflict-free b128 reads:
// bsw[st][kc][wave][u][quad][nl][kl]  (kc=k>>5, quad=(k>>3)&3, kl=k&7,
//                                     wave=c>>7, u=(c>>4)&7, nl=c&15)
__global__ void k_wb(const float* __restrict__ W, const float* __restrict__ w_ih,
                     const float* __restrict__ w_hh, u16* __restrict__ bsw) {
  __shared__ float wrow[128];
  int b = blockIdx.x, st = b >> 8, k = b & 255, t = threadIdx.x;
  if (k < 128) wrow[t] = W[(st * 128 + k) * 128 + t];
  __syncthreads();
  int kc = k >> 5, quad = (k >> 3) & 3, kl = k & 7;
  u16* base = bsw + (size_t)st * 131072 + kc * 16384;
  int u = t >> 4, nl = t & 15;
  #pragma unroll
  for (int gq = 0; gq < 4; ++gq) {
    int c = gq * 128 + t;
    float v;
    if (k < 128) {
      if (c < 384) {
        const float* wr = w_ih + c * 128;
        float sacc = 0.f;
        for (int j = 0; j < 128; ++j) sacc += wrow[j] * wr[j];
        v = sacc;
      } else v = 0.f;
    } else {
      int kk = k - 128;
      if (c < 256)      v = w_hh[c * 128 + kk];
      else if (c < 384) v = 0.f;
      else              v = w_hh[(c - 128) * 128 + kk];
    }
    base[((gq * 8 + u) * 4 + quad) * 128 + nl * 8 + kl] = f2bf(v);
  }
}

// ---------------- x -> bf16 ----------------
__global__ void k_convert(const float* __restrict__ x, u16* __restrict__ h) {
  int i = (blockIdx.x * 256 + threadIdx.x) * 4;
  float4 v = *(const float4*)(x + i);
  u16 o[4] = {f2bf(v.x), f2bf(v.y), f2bf(v.z), f2bf(v.w)};
  *(uint2*)(h + i) = *(uint2*)o;
}

// ---------------- neighbor gather-sum: s[dst] = sum h[src] ----------------
__global__ void k_gather(const u16* __restrict__ h, const int* __restrict__ csr,
                         const int* __restrict__ offs, u16* __restrict__ s) {
  int node = blockIdx.x * 4 + (threadIdx.x >> 6);
  int lane = threadIdx.x & 63;
  int q   = lane >> 4;
  int sub = lane & 15;
  int beg = offs[node], end = offs[node + 1];
  float a0 = 0.f, a1 = 0.f, a2 = 0.f, a3 = 0.f;
  float a4 = 0.f, a5 = 0.f, a6 = 0.f, a7 = 0.f;
  for (int j = beg + q; j < end; j += 4) {
    int src = csr[j];
    uint4 p = *(const uint4*)(h + (size_t)src * 128 + sub * 8);
    a0 += bf2f((u16)(p.x & 0xffffu)); a1 += bf2f((u16)(p.x >> 16));
    a2 += bf2f((u16)(p.y & 0xffffu)); a3 += bf2f((u16)(p.y >> 16));
    a4 += bf2f((u16)(p.z & 0xffffu)); a5 += bf2f((u16)(p.z >> 16));
    a6 += bf2f((u16)(p.w & 0xffffu)); a7 += bf2f((u16)(p.w >> 16));
  }
  a0 += __shfl_xor(a0, 16); a0 += __shfl_xor(a0, 32);
  a1 += __shfl_xor(a1, 16); a1 += __shfl_xor(a1, 32);
  a2 += __shfl_xor(a2, 16); a2 += __shfl_xor(a2, 32);
  a3 += __shfl_xor(a3, 16); a3 += __shfl_xor(a3, 32);
  a4 += __shfl_xor(a4, 16); a4 += __shfl_xor(a4, 32);
  a5 += __shfl_xor(a5, 16); a5 += __shfl_xor(a5, 32);
  a6 += __shfl_xor(a6, 16); a6 += __shfl_xor(a6, 32);
  a7 += __shfl_xor(a7, 16); a7 += __shfl_xor(a7, 32);
  if (q == 0) {
    uint4 o;
    o.x = (u32)f2bf(a0) | ((u32)f2bf(a1) << 16);
    o.y = (u32)f2bf(a2) | ((u32)f2bf(a3) << 16);
    o.z = (u32)f2bf(a4) | ((u32)f2bf(a5) << 16);
    o.w = (u32)f2bf(a6) | ((u32)f2bf(a7) << 16);
    *(uint4*)(s + (size_t)node * 128 + sub * 8) = o;
  }
}

// ---------------- fused dual-GEMM + GRU cell ----------------
// 64 rows/block, 4 waves, wave w owns cols w*128..+127 (w0=r, w1=z, w2=i_n, w3=h_n).
// All LDS frag reads are base+lane*16 (contiguous 1KB per wave64 b128 = conflict-free).
// Asw: [g][kc][quad][nl][kl] (g = 16-row group). Bsw: one kc chunk, global order.
// Gate exchange in two 32-row half-passes reusing Bsw (pitch GATE_P).
__global__ __launch_bounds__(256) void k_gemm_gru(
    const u16* __restrict__ s_mat, const u16* __restrict__ h_mat,
    const u16* __restrict__ bsw, const float* __restrict__ b_ih,
    const float* __restrict__ b_hh, u16* __restrict__ h_out) {
  __shared__ u16 Asw[16384];          // 32 KB: A = [s|h], 64 rows x 256 k
  __shared__ u16 Bsw[4 * 32 * GATE_P];// 34.8 KB: B kc-chunk (first 32KB) / gate buffers

  const int tid  = threadIdx.x;
  const int wave = tid >> 6;
  const int lane = tid & 63;
  const int nl   = lane & 15;
  const int quad = lane >> 4;
  const int row0 = blockIdx.x * 64;

  {  // stage A: thread (g=wave, squad, snl) loads 8x16B; LDS writes contiguous/wave
    int snl = tid & 15, squad = (tid >> 4) & 3, g = tid >> 6;
    int r = row0 + g * 16 + snl;          // rows >= N_NODES read in-ws garbage (unstored)
    const u16* srow = s_mat + (size_t)r * 128;
    const u16* hrow = h_mat + (size_t)r * 128;
    #pragma unroll
    for (int kc = 0; kc < 4; ++kc) {
      uint4 v = *(const uint4*)(srow + kc * 32 + squad * 8);
      *(uint4*)&Asw[(((g * 8 + kc) * 4 + squad) * 16 + snl) * 8] = v;
    }
    #pragma unroll
    for (int kc = 0; kc < 4; ++kc) {
      uint4 v = *(const uint4*)(hrow + kc * 32 + squad * 8);
      *(uint4*)&Asw[(((g * 8 + kc + 4) * 4 + squad) * 16 + snl) * 8] = v;
    }
  }

  f32x4 acc[4][8];
  #pragma unroll
  for (int g = 0; g < 4; ++g)
    #pragma unroll
    for (int u = 0; u < 8; ++u) acc[g][u] = (f32x4){0.f, 0.f, 0.f, 0.f};

  for (int kc = 0; kc < 8; ++kc) {
    const u16* gsrc = bsw + kc * 16384;  // 32KB contiguous chunk, same layout as LDS
    #pragma unroll
    for (int i = 0; i < 8; ++i) {
      int inst = wave * 8 + i;
      gl_lds16(gsrc + inst * 512 + lane * 8, Bsw + inst * 512);
    }
    __syncthreads();
    bf16x8 a[4];
    #pragma unroll
    for (int g = 0; g < 4; ++g)
      a[g] = *(const bf16x8*)&Asw[(g * 8 + kc) * 512 + lane * 8];
    #pragma unroll
    for (int u = 0; u < 8; ++u) {
      bf16x8 bf = *(const bf16x8*)&Bsw[(wave * 8 + u) * 512 + lane * 8];
      #pragma unroll
      for (int g = 0; g < 4; ++g)
        acc[g][u] = __builtin_amdgcn_mfma_f32_16x16x32_bf16(a[g], bf, acc[g][u], 0, 0, 0);
    }
    __syncthreads();
  }

  float biasv[8];
  #pragma unroll
  for (int u = 0; u < 8; ++u) {
    int cl = u * 16 + nl;
    biasv[u] = (wave == 0) ? b_ih[cl] + b_hh[cl]
             : (wave == 1) ? b_ih[128 + cl] + b_hh[128 + cl]
             : (wave == 2) ? b_ih[256 + cl]
                           : b_hh[256 + cl];
  }

  #pragma unroll
  for (int half = 0; half < 2; ++half) {
    if (half) __syncthreads();  // previous combine done reading Bsw
    u16* gb = Bsw + wave * (32 * GATE_P);
    #pragma unroll
    for (int gg = 0; gg < 2; ++gg) {
      int g = half * 2 + gg;
      #pragma unroll
      for (int u = 0; u < 8; ++u) {
        int cl = u * 16 + nl;
        #pragma unroll
        for (int i = 0; i < 4; ++i) {
          int m = gg * 16 + quad * 4 + i;
          float v = acc[g][u][i] + biasv[u];
          if (wave < 2) v = fast_sig(v);
          gb[m * GATE_P + cl] = f2bf(v);
        }
      }
    }
    __syncthreads();
    {  // combine 32 rows: h' = (1-z)*n + z*h, n = tanh(i_n + r*h_n)
      int r32 = tid >> 3, c0 = (tid & 7) * 16;
      int rloc = half * 32 + r32;
      int grow = rloc >> 4, nr = rloc & 15;
      u16 hbuf[16];
      int kch = 4 + (c0 >> 5);
      int q0  = (c0 >> 3) & 3;
      *(uint4*)&hbuf[0] = *(const uint4*)&Asw[(((grow * 8 + kch) * 4 + q0) * 16 + nr) * 8];
      *(uint4*)&hbuf[8] = *(const uint4*)&Asw[(((grow * 8 + kch) * 4 + q0 + 1) * 16 + nr) * 8];
      u16 rb[16], zb[16], ib[16], nb[16];
      const u16* g_r  = Bsw;
      const u16* g_z  = Bsw + 32 * GATE_P;
      const u16* g_in = Bsw + 64 * GATE_P;
      const u16* g_hn = Bsw + 96 * GATE_P;
      *(uint4*)&rb[0] = *(const uint4*)&g_r[r32 * GATE_P + c0];
      *(uint4*)&rb[8] = *(const uint4*)&g_r[r32 * GATE_P + c0 + 8];
      *(uint4*)&zb[0] = *(const uint4*)&g_z[r32 * GATE_P + c0];
      *(uint4*)&zb[8] = *(const uint4*)&g_z[r32 * GATE_P + c0 + 8];
      *(uint4*)&ib[0] = *(const uint4*)&g_in[r32 * GATE_P + c0];
      *(uint4*)&ib[8] = *(const uint4*)&g_in[r32 * GATE_P + c0 + 8];
      *(uint4*)&nb[0] = *(const uint4*)&g_hn[r32 * GATE_P + c0];
      *(uint4*)&nb[8] = *(const uint4*)&g_hn[r32 * GATE_P + c0 + 8];
      u16 outv[16];
      #pragma unroll
      for (int c = 0; c < 16; ++c) {
        float rv = bf2f(rb[c]);
        float zv = bf2f(zb[c]);
        float iv = bf2f(ib[c]);
        float hn = bf2f(nb[c]);
        float hv = bf2f(hbuf[c]);
        float n  = fast_tanh(iv + rv * hn);
        outv[c]  = f2bf((1.f - zv) * n + zv * hv);
      }
      int rg = row0 + rloc;
      if (rg < N_NODES) {
        uint4* dstp = (uint4*)(h_out + (size_t)rg * 128 + c0);
        dstp[0] = *(uint4*)&outv[0];
        dstp[1] = *(uint4*)&outv[8];
      }
    }
  }
}

// ---------------- relu + segment mean pool (two-phase, parallel) ----------------
__global__ void k_pool_partial(const u16* __restrict__ h, const int* __restrict__ batch,
                               float* __restrict__ acc) {
  int t = threadIdx.x;  // column 0..127
  int node0 = blockIdx.x * 125;
  int node1 = node0 + 125;
  int cur = batch[node0];
  float sum = 0.f;
  for (int r = node0; r < node1; ++r) {
    int g = batch[r];
    if (g != cur) {
      atomicAdd(&acc[cur * 128 + t], sum);
      sum = 0.f;
      cur = g;
    }
    sum += fmaxf(bf2f(h[(size_t)r * 128 + t]), 0.f);
  }
  atomicAdd(&acc[cur * 128 + t], sum);
}

__global__ void k_pool_div(const float* __restrict__ acc, const int* __restrict__ batch,
                           float* __restrict__ out) {
  __shared__ int se[2];
  int g = blockIdx.x, t = threadIdx.x;
  if (t < 2) {
    int target = g + t;
    int lo = 0, hi = N_NODES;
    while (lo < hi) { int mid = (lo + hi) >> 1; if (batch[mid] < target) lo = mid + 1; else hi = mid; }
    se[t] = lo;
  }
  __syncthreads();
  int cnt = se[1] - se[0];
  out[g * 128 + t] = acc[g * 128 + t] / (float)(cnt > 0 ? cnt : 1);
}

extern "C" void kernel_launch(void* const* d_in, const int* in_sizes, int n_in,
                              void* d_out, int out_size, void* d_ws, size_t ws_size,
                              hipStream_t stream) {
  const float* x     = (const float*)d_in[0];
  const int*   edges = (const int*)d_in[1];
  const int*   batch = (const int*)d_in[2];
  const float* W     = (const float*)d_in[3];
  const float* w_ih  = (const float*)d_in[4];
  const float* w_hh  = (const float*)d_in[5];
  const float* b_ih  = (const float*)d_in[6];
  const float* b_hh  = (const float*)d_in[7];
  float* out = (float*)d_out;

  char* w = (char*)d_ws;
  u16* buf0    = (u16*)(w);                 // 25,600,000 B  (h / s ping)
  u16* buf1    = (u16*)(w + 25600000);      // 25,600,000 B  (h / s pong)
  u16* bsw     = (u16*)(w + 51200000);      // 1,048,576 B
  int* counts  = (int*)(w + 52300032);      // 400,000 B  (reused as pool acc)
  int* offs    = (int*)(w + 52710400);      // 400,004 B
  int* gcursor = (int*)(w + 53120768);      // 1,024 B
  int* csr     = (int*)(w + 53531136);      // 6,400,000 B
  int* bsum    = (int*)(w + 59931136);      // 392 B
  int* bbase   = (int*)(w + 59931648);      // 392 B  -> total ~60 MB
  float* acc   = (float*)counts;            // counts dead after scan
  u64* ebuf    = (u64*)buf1;                // 12.8 MB; buf1 dead until 1st gather

  const int* esrc = edges;
  const int* edst = edges + N_EDGES;

  hipMemsetAsync(counts, 0, N_NODES * sizeof(int), stream);
  k_hist<<<N_EDGES / 256, 256, 0, stream>>>(edst, counts);
  k_scan_blk<<<98, 1024, 0, stream>>>(counts, offs, bsum);
  k_scan_mid<<<1, 128, 0, stream>>>(bsum, bbase);
  k_scan_fin<<<98, 1024, 0, stream>>>(counts, offs, bbase);
  k_binit<<<1, NBUCK, 0, stream>>>(offs, gcursor);
  k_part<<<391, 1024, 0, stream>>>(esrc, edst, gcursor, ebuf);
  k_csr<<<NBUCK, 1024, 0, stream>>>(ebuf, offs, csr);
  k_wb<<<1024, 128, 0, stream>>>(W, w_ih, w_hh, bsw);
  k_convert<<<(N_NODES * HIDDEN) / 1024, 256, 0, stream>>>(x, buf0);
  hipMemsetAsync(acc, 0, N_GRAPHS * HIDDEN * sizeof(float), stream);

  u16* hcur = buf0;
  u16* hnxt = buf1;
  for (int st = 0; st < STEPS; ++st) {
    k_gather<<<N_NODES / 4, 256, 0, stream>>>(hcur, csr, offs, hnxt);
    // in-place: each block reads only its own 64 rows of s (hnxt) and h (hcur)
    // into LDS before writing h_out (hnxt) over those same rows.
    k_gemm_gru<<<(N_NODES + 63) / 64, 256, 0, stream>>>(hnxt, hcur, bsw + st * 131072,
                                                        b_ih, b_hh, hnxt);
    u16* tmp = hcur; hcur = hnxt; hnxt = tmp;
  }
  k_pool_partial<<<800, 128, 0, stream>>>(hcur, batch, acc);
  k_pool_div<<<N_GRAPHS, 128, 0, stream>>>(acc, batch, out);
}

// Round 6
// 761.920 us; speedup vs baseline: 1.3354x; 1.3354x over previous
//
#include <hip/hip_runtime.h>

#define N_NODES  100000
#define N_EDGES  1600000
#define HIDDEN   128
#define STEPS    4
#define N_GRAPHS 64
#define NBUCK    256
#define BWID     391   // nodes per bucket: 256*391 = 100096 >= 100000
#define OUT_P    136   // output-staging row pitch (u16)

typedef unsigned short u16;
typedef unsigned int   u32;
typedef unsigned long long u64;
typedef __attribute__((ext_vector_type(8))) short bf16x8;
typedef __attribute__((ext_vector_type(4))) float f32x4;

__device__ inline u16 f2bf(float f) {
  u32 u = __float_as_uint(f);
  u = (u + 0x7FFFu + ((u >> 16) & 1u)) >> 16;  // RTNE
  return (u16)u;
}
__device__ inline float bf2f(u16 b) { return __uint_as_float(((u32)b) << 16); }

__device__ inline float fast_sig(float x) { return 1.f / (1.f + __expf(-x)); }
__device__ inline float fast_tanh(float x) {
  x = fminf(fmaxf(x, -15.f), 15.f);
  float e = __expf(2.f * x);
  return (e - 1.f) / (e + 1.f);
}

__device__ inline void gl_lds16(const void* g, void* l) {
  __builtin_amdgcn_global_load_lds((const __attribute__((address_space(1))) void*)g,
                                   (__attribute__((address_space(3))) void*)l, 16, 0, 0);
}

// ---------------- CSR build ----------------
__global__ void k_hist(const int* __restrict__ dst, int* __restrict__ counts) {
  int e = blockIdx.x * 256 + threadIdx.x;
  atomicAdd(&counts[dst[e]], 1);
}

__global__ void k_scan_blk(const int* __restrict__ counts, int* __restrict__ offs,
                           int* __restrict__ bsum) {
  __shared__ int buf[1024];
  int gid = blockIdx.x * 1024 + threadIdx.x;
  int v = (gid < N_NODES) ? counts[gid] : 0;
  buf[threadIdx.x] = v;
  __syncthreads();
  for (int off = 1; off < 1024; off <<= 1) {
    int t = 0;
    if (threadIdx.x >= off) t = buf[threadIdx.x - off];
    __syncthreads();
    buf[threadIdx.x] += t;
    __syncthreads();
  }
  if (gid < N_NODES) offs[gid] = buf[threadIdx.x];  // inclusive (temp)
  if (threadIdx.x == 1023) bsum[blockIdx.x] = buf[1023];
}

__global__ void k_scan_mid(const int* __restrict__ bsum, int* __restrict__ bbase) {
  __shared__ int buf[128];
  int t = threadIdx.x;
  int v = (t < 98) ? bsum[t] : 0;
  buf[t] = v;
  __syncthreads();
  for (int off = 1; off < 128; off <<= 1) {
    int u = 0;
    if (t >= off) u = buf[t - off];
    __syncthreads();
    buf[t] += u;
    __syncthreads();
  }
  if (t < 98) bbase[t] = buf[t] - v;
}

__global__ void k_scan_fin(const int* __restrict__ counts, int* __restrict__ offs,
                           const int* __restrict__ bbase) {
  int gid = blockIdx.x * 1024 + threadIdx.x;
  if (gid >= N_NODES) return;
  int c = counts[gid];
  int ex = bbase[blockIdx.x] + offs[gid] - c;
  offs[gid] = ex;
  if (gid == N_NODES - 1) offs[N_NODES] = ex + c;
}

__global__ void k_binit(const int* __restrict__ offs, int* __restrict__ gcursor) {
  int t = threadIdx.x;
  gcursor[t] = offs[t * BWID];
}

__global__ __launch_bounds__(1024) void k_part(const int* __restrict__ esrc,
                                               const int* __restrict__ edst,
                                               int* __restrict__ gcursor,
                                               u64* __restrict__ ebuf) {
  __shared__ int hist[NBUCK];
  __shared__ int base[NBUCK];
  int tid = threadIdx.x;
  if (tid < NBUCK) hist[tid] = 0;
  __syncthreads();
  int e0 = blockIdx.x * 4096;
  int sv[4], dv[4], bk[4], rk[4];
  #pragma unroll
  for (int i = 0; i < 4; ++i) {
    int e = e0 + i * 1024 + tid;
    if (e < N_EDGES) {
      sv[i] = esrc[e];
      dv[i] = edst[e];
      bk[i] = (int)((u32)dv[i] / (u32)BWID);
      rk[i] = atomicAdd(&hist[bk[i]], 1);
    } else bk[i] = -1;
  }
  __syncthreads();
  if (tid < NBUCK) base[tid] = atomicAdd(&gcursor[tid], hist[tid]);
  __syncthreads();
  #pragma unroll
  for (int i = 0; i < 4; ++i) {
    if (bk[i] >= 0) {
      int pos = base[bk[i]] + rk[i];
      ebuf[pos] = ((u64)(u32)dv[i] << 32) | (u32)sv[i];
    }
  }
}

__global__ __launch_bounds__(1024) void k_csr(const u64* __restrict__ ebuf,
                                              const int* __restrict__ offs,
                                              int* __restrict__ csr) {
  __shared__ int lcur[BWID];
  int b = blockIdx.x, tid = threadIdx.x;
  int n0 = b * BWID;
  int n1 = min(n0 + BWID, N_NODES);
  int nn = n1 - n0;
  if (tid < nn) lcur[tid] = offs[n0 + tid];
  __syncthreads();
  int e0 = offs[n0], e1 = offs[n1];
  for (int e = e0 + tid; e < e1; e += 1024) {
    u64 p = ebuf[e];
    int src = (int)(p & 0xffffffffull);
    int dst = (int)(p >> 32);
    int pos = atomicAdd(&lcur[dst - n0], 1);
    csr[pos] = src;
  }
}

// ---------------- combined weight build ----------------
// Column-interleaved fragment order: per kc chunk (32 k), slot = wave*8 + u with
// u = gate*2 + hu; slot covers B column c = gate*128 + wave*32 + hu*16 + nl.
// Address: bsw[st][kc][slot][quad][nl][kl]  (quad=(k>>3)&3, kl=k&7).
// Wave w thus computes ALL FOUR gate values for its own 32 output columns.
__global__ void k_wb(const float* __restrict__ W, const float* __restrict__ w_ih,
                     const float* __restrict__ w_hh, u16* __restrict__ bsw) {
  __shared__ float wrow[128];
  int b = blockIdx.x, st = b >> 8, k = b & 255, t = threadIdx.x;
  if (k < 128) wrow[t] = W[(st * 128 + k) * 128 + t];
  __syncthreads();
  int kc = k >> 5, quad = (k >> 3) & 3, kl = k & 7;
  u16* base = bsw + (size_t)st * 131072 + kc * 16384;
  #pragma unroll
  for (int gq = 0; gq < 4; ++gq) {
    int c = gq * 128 + t;
    float v;
    if (k < 128) {
      if (c < 384) {
        const float* wr = w_ih + c * 128;
        float sacc = 0.f;
        for (int j = 0; j < 128; ++j) sacc += wrow[j] * wr[j];
        v = sacc;
      } else v = 0.f;
    } else {
      int kk = k - 128;
      if (c < 256)      v = w_hh[c * 128 + kk];
      else if (c < 384) v = 0.f;
      else              v = w_hh[(c - 128) * 128 + kk];
    }
    int gi = c >> 7, cw = c & 127;
    int wv = cw >> 5, hu = (cw >> 4) & 1, nl = c & 15;
    int slot = wv * 8 + gi * 2 + hu;
    base[(slot * 4 + quad) * 128 + nl * 8 + kl] = f2bf(v);
  }
}

// ---------------- x -> bf16 ----------------
__global__ void k_convert(const float* __restrict__ x, u16* __restrict__ h) {
  int i = (blockIdx.x * 256 + threadIdx.x) * 4;
  float4 v = *(const float4*)(x + i);
  u16 o[4] = {f2bf(v.x), f2bf(v.y), f2bf(v.z), f2bf(v.w)};
  *(uint2*)(h + i) = *(uint2*)o;
}

// ---------------- neighbor gather-sum: s[dst] = sum h[src] ----------------
__global__ void k_gather(const u16* __restrict__ h, const int* __restrict__ csr,
                         const int* __restrict__ offs, u16* __restrict__ s) {
  int node = blockIdx.x * 4 + (threadIdx.x >> 6);
  int lane = threadIdx.x & 63;
  int q   = lane >> 4;
  int sub = lane & 15;
  int beg = offs[node], end = offs[node + 1];
  float a0 = 0.f, a1 = 0.f, a2 = 0.f, a3 = 0.f;
  float a4 = 0.f, a5 = 0.f, a6 = 0.f, a7 = 0.f;
  for (int j = beg + q; j < end; j += 4) {
    int src = csr[j];
    uint4 p = *(const uint4*)(h + (size_t)src * 128 + sub * 8);
    a0 += bf2f((u16)(p.x & 0xffffu)); a1 += bf2f((u16)(p.x >> 16));
    a2 += bf2f((u16)(p.y & 0xffffu)); a3 += bf2f((u16)(p.y >> 16));
    a4 += bf2f((u16)(p.z & 0xffffu)); a5 += bf2f((u16)(p.z >> 16));
    a6 += bf2f((u16)(p.w & 0xffffu)); a7 += bf2f((u16)(p.w >> 16));
  }
  a0 += __shfl_xor(a0, 16); a0 += __shfl_xor(a0, 32);
  a1 += __shfl_xor(a1, 16); a1 += __shfl_xor(a1, 32);
  a2 += __shfl_xor(a2, 16); a2 += __shfl_xor(a2, 32);
  a3 += __shfl_xor(a3, 16); a3 += __shfl_xor(a3, 32);
  a4 += __shfl_xor(a4, 16); a4 += __shfl_xor(a4, 32);
  a5 += __shfl_xor(a5, 16); a5 += __shfl_xor(a5, 32);
  a6 += __shfl_xor(a6, 16); a6 += __shfl_xor(a6, 32);
  a7 += __shfl_xor(a7, 16); a7 += __shfl_xor(a7, 32);
  if (q == 0) {
    uint4 o;
    o.x = (u32)f2bf(a0) | ((u32)f2bf(a1) << 16);
    o.y = (u32)f2bf(a2) | ((u32)f2bf(a3) << 16);
    o.z = (u32)f2bf(a4) | ((u32)f2bf(a5) << 16);
    o.w = (u32)f2bf(a6) | ((u32)f2bf(a7) << 16);
    *(uint4*)(s + (size_t)node * 128 + sub * 8) = o;
  }
}

// ---------------- fused dual-GEMM + GRU cell ----------------
// 32 rows/block (3125 blocks), 4 waves. Wave w owns output cols w*32..w*32+31 and
// computes all 4 gates for them (column-interleaved B) -> GRU combine is pure
// register math, no gate LDS exchange. All wave64 frag reads are base+lane*16
// (conflict-free). Output staged through Bsw for coalesced uint4 stores.
__global__ __launch_bounds__(256) void k_gemm_gru(
    const u16* __restrict__ s_mat, const u16* __restrict__ h_mat,
    const u16* __restrict__ bsw, const float* __restrict__ b_ih,
    const float* __restrict__ b_hh, u16* __restrict__ h_out) {
  __shared__ u16 Asw[8192];    // 16 KB: A=[s|h], 32 rows x 256 k, [g][kslot][quad][nl][kl]
  __shared__ u16 Bsw[16384];   // 32 KB: one kc chunk of B; reused as out-stage [32][OUT_P]

  const int tid  = threadIdx.x;
  const int wave = tid >> 6;
  const int lane = tid & 63;
  const int nl   = lane & 15;
  const int quad = lane >> 4;
  const int row0 = blockIdx.x * 32;   // 3125 * 32 == 100000 exactly

  {  // stage A: thread (half, squad, snl) loads 4x16B; contiguous LDS writes per wave
    int snl = tid & 15, squad = (tid >> 4) & 3, sel = tid >> 6;
    int g = sel & 1, half = sel >> 1;             // g: 16-row group; half: 0=s, 1=h
    const u16* row = (half ? h_mat : s_mat) + (size_t)(row0 + g * 16 + snl) * 128;
    #pragma unroll
    for (int kc2 = 0; kc2 < 4; ++kc2) {
      uint4 v = *(const uint4*)(row + kc2 * 32 + squad * 8);
      *(uint4*)&Asw[(((g * 8 + half * 4 + kc2) * 4 + squad) * 16 + snl) * 8] = v;
    }
  }

  f32x4 acc[2][8];
  #pragma unroll
  for (int g = 0; g < 2; ++g)
    #pragma unroll
    for (int u = 0; u < 8; ++u) acc[g][u] = (f32x4){0.f, 0.f, 0.f, 0.f};

  for (int kc = 0; kc < 8; ++kc) {
    const u16* gsrc = bsw + kc * 16384;  // 32KB contiguous chunk, same layout as LDS
    #pragma unroll
    for (int i = 0; i < 8; ++i) {
      int inst = wave * 8 + i;
      gl_lds16(gsrc + inst * 512 + lane * 8, Bsw + inst * 512);
    }
    __syncthreads();
    bf16x8 a[2];
    a[0] = *(const bf16x8*)&Asw[kc * 512 + lane * 8];
    a[1] = *(const bf16x8*)&Asw[(8 + kc) * 512 + lane * 8];
    #pragma unroll
    for (int u = 0; u < 8; ++u) {
      bf16x8 bf = *(const bf16x8*)&Bsw[(wave * 8 + u) * 512 + lane * 8];
      acc[0][u] = __builtin_amdgcn_mfma_f32_16x16x32_bf16(a[0], bf, acc[0][u], 0, 0, 0);
      acc[1][u] = __builtin_amdgcn_mfma_f32_16x16x32_bf16(a[1], bf, acc[1][u], 0, 0, 0);
    }
    __syncthreads();
  }

  // biases: u = gate*2+hu, within-gate col cw = wave*32 + hu*16 + nl
  float bias[8];
  #pragma unroll
  for (int u = 0; u < 8; ++u) {
    int gi = u >> 1, hu = u & 1;
    int cw = wave * 32 + hu * 16 + nl;
    bias[u] = (gi == 0) ? b_ih[cw] + b_hh[cw]
            : (gi == 1) ? b_ih[128 + cw] + b_hh[128 + cw]
            : (gi == 2) ? b_ih[256 + cw]
                        : b_hh[256 + cw];
  }

  // register-resident GRU combine; results -> Bsw out-stage (safe: last K-loop
  // sync guarantees all frag reads of Bsw are done)
  #pragma unroll
  for (int g = 0; g < 2; ++g) {
    #pragma unroll
    for (int hu = 0; hu < 2; ++hu) {
      int cw = wave * 32 + hu * 16 + nl;     // output column
      // h value location in Asw: k = 128 + cw
      int hbase = ((g * 8 + 4 + wave) * 4 + ((hu * 2 + (nl >> 3)) & 3)) * 128 + (nl & 7);
      #pragma unroll
      for (int i = 0; i < 4; ++i) {
        int m = quad * 4 + i;                // row within 16-row group
        float rv = fast_sig(acc[g][0 + hu][i] + bias[0 + hu]);
        float zv = fast_sig(acc[g][2 + hu][i] + bias[2 + hu]);
        float iv = acc[g][4 + hu][i] + bias[4 + hu];
        float hn = acc[g][6 + hu][i] + bias[6 + hu];
        float hv = bf2f(Asw[hbase + m * 8]);
        float n  = fast_tanh(iv + rv * hn);
        float o  = (1.f - zv) * n + zv * hv;
        Bsw[(g * 16 + m) * OUT_P + cw] = f2bf(o);
      }
    }
  }
  __syncthreads();

  {  // coalesced store: 32 rows x 128 cols
    int r32 = tid >> 3, c0 = (tid & 7) * 16;
    uint4 v0 = *(const uint4*)&Bsw[r32 * OUT_P + c0];
    uint4 v1 = *(const uint4*)&Bsw[r32 * OUT_P + c0 + 8];
    uint4* dstp = (uint4*)(h_out + (size_t)(row0 + r32) * 128 + c0);
    dstp[0] = v0;
    dstp[1] = v1;
  }
}

// ---------------- relu + segment mean pool (two-phase, parallel) ----------------
__global__ void k_pool_partial(const u16* __restrict__ h, const int* __restrict__ batch,
                               float* __restrict__ acc) {
  int t = threadIdx.x;  // column 0..127
  int node0 = blockIdx.x * 125;
  int node1 = node0 + 125;
  int cur = batch[node0];
  float sum = 0.f;
  for (int r = node0; r < node1; ++r) {
    int g = batch[r];
    if (g != cur) {
      atomicAdd(&acc[cur * 128 + t], sum);
      sum = 0.f;
      cur = g;
    }
    sum += fmaxf(bf2f(h[(size_t)r * 128 + t]), 0.f);
  }
  atomicAdd(&acc[cur * 128 + t], sum);
}

__global__ void k_pool_div(const float* __restrict__ acc, const int* __restrict__ batch,
                           float* __restrict__ out) {
  __shared__ int se[2];
  int g = blockIdx.x, t = threadIdx.x;
  if (t < 2) {
    int target = g + t;
    int lo = 0, hi = N_NODES;
    while (lo < hi) { int mid = (lo + hi) >> 1; if (batch[mid] < target) lo = mid + 1; else hi = mid; }
    se[t] = lo;
  }
  __syncthreads();
  int cnt = se[1] - se[0];
  out[g * 128 + t] = acc[g * 128 + t] / (float)(cnt > 0 ? cnt : 1);
}

extern "C" void kernel_launch(void* const* d_in, const int* in_sizes, int n_in,
                              void* d_out, int out_size, void* d_ws, size_t ws_size,
                              hipStream_t stream) {
  const float* x     = (const float*)d_in[0];
  const int*   edges = (const int*)d_in[1];
  const int*   batch = (const int*)d_in[2];
  const float* W     = (const float*)d_in[3];
  const float* w_ih  = (const float*)d_in[4];
  const float* w_hh  = (const float*)d_in[5];
  const float* b_ih  = (const float*)d_in[6];
  const float* b_hh  = (const float*)d_in[7];
  float* out = (float*)d_out;

  char* w = (char*)d_ws;
  u16* buf0    = (u16*)(w);                 // 25,600,000 B  (h / s ping)
  u16* buf1    = (u16*)(w + 25600000);      // 25,600,000 B  (h / s pong)
  u16* bsw     = (u16*)(w + 51200000);      // 1,048,576 B
  int* counts  = (int*)(w + 52300032);      // 400,000 B  (reused as pool acc)
  int* offs    = (int*)(w + 52710400);      // 400,004 B
  int* gcursor = (int*)(w + 53120768);      // 1,024 B
  int* csr     = (int*)(w + 53531136);      // 6,400,000 B
  int* bsum    = (int*)(w + 59931136);      // 392 B
  int* bbase   = (int*)(w + 59931648);      // 392 B  -> total ~60 MB
  float* acc   = (float*)counts;            // counts dead after scan
  u64* ebuf    = (u64*)buf1;                // 12.8 MB; buf1 dead until 1st gather

  const int* esrc = edges;
  const int* edst = edges + N_EDGES;

  hipMemsetAsync(counts, 0, N_NODES * sizeof(int), stream);
  k_hist<<<N_EDGES / 256, 256, 0, stream>>>(edst, counts);
  k_scan_blk<<<98, 1024, 0, stream>>>(counts, offs, bsum);
  k_scan_mid<<<1, 128, 0, stream>>>(bsum, bbase);
  k_scan_fin<<<98, 1024, 0, stream>>>(counts, offs, bbase);
  k_binit<<<1, NBUCK, 0, stream>>>(offs, gcursor);
  k_part<<<391, 1024, 0, stream>>>(esrc, edst, gcursor, ebuf);
  k_csr<<<NBUCK, 1024, 0, stream>>>(ebuf, offs, csr);
  k_wb<<<1024, 128, 0, stream>>>(W, w_ih, w_hh, bsw);
  k_convert<<<(N_NODES * HIDDEN) / 1024, 256, 0, stream>>>(x, buf0);
  hipMemsetAsync(acc, 0, N_GRAPHS * HIDDEN * sizeof(float), stream);

  u16* hcur = buf0;
  u16* hnxt = buf1;
  for (int st = 0; st < STEPS; ++st) {
    k_gather<<<N_NODES / 4, 256, 0, stream>>>(hcur, csr, offs, hnxt);
    // in-place: each block reads only its own 32 rows of s (hnxt) and h (hcur)
    // into LDS before writing h_out (hnxt) over those same rows.
    k_gemm_gru<<<N_NODES / 32, 256, 0, stream>>>(hnxt, hcur, bsw + st * 131072,
                                                 b_ih, b_hh, hnxt);
    u16* tmp = hcur; hcur = hnxt; hnxt = tmp;
  }
  k_pool_partial<<<800, 128, 0, stream>>>(hcur, batch, acc);
  k_pool_div<<<N_GRAPHS, 128, 0, stream>>>(acc, batch, out);
}

// Round 7
// 698.438 us; speedup vs baseline: 1.4567x; 1.0909x over previous
//
#include <hip/hip_runtime.h>

#define N_NODES  100000
#define N_EDGES  1600000
#define HIDDEN   128
#define STEPS    4
#define N_GRAPHS 64
#define NBUCK    256
#define BWID     391   // nodes per bucket: 256*391 = 100096 >= 100000
#define OUT_P    136   // output-staging row pitch (u16)

typedef unsigned short u16;
typedef unsigned int   u32;
typedef unsigned long long u64;
typedef __attribute__((ext_vector_type(8))) short bf16x8;
typedef __attribute__((ext_vector_type(4))) float f32x4;

__device__ inline u16 f2bf(float f) {
  u32 u = __float_as_uint(f);
  u = (u + 0x7FFFu + ((u >> 16) & 1u)) >> 16;  // RTNE
  return (u16)u;
}
__device__ inline float bf2f(u16 b) { return __uint_as_float(((u32)b) << 16); }

__device__ inline float fast_sig(float x) { return 1.f / (1.f + __expf(-x)); }
__device__ inline float fast_tanh(float x) {
  x = fminf(fmaxf(x, -15.f), 15.f);
  float e = __expf(2.f * x);
  return (e - 1.f) / (e + 1.f);
}

__device__ inline void gl_lds16(const void* g, void* l) {
  __builtin_amdgcn_global_load_lds((const __attribute__((address_space(1))) void*)g,
                                   (__attribute__((address_space(3))) void*)l, 16, 0, 0);
}

// ---------------- CSR build (bucketed, no global per-node atomics) ----------------
// Per-bucket histogram: LDS hist + 256 global atomics per block.
__global__ __launch_bounds__(1024) void k_bhist(const int* __restrict__ edst,
                                                int* __restrict__ bcnt) {
  __shared__ int hist[NBUCK];
  int tid = threadIdx.x;
  if (tid < NBUCK) hist[tid] = 0;
  __syncthreads();
  int e0 = blockIdx.x * 4096;
  #pragma unroll
  for (int i = 0; i < 4; ++i) {
    int e = e0 + i * 1024 + tid;
    if (e < N_EDGES) atomicAdd(&hist[(u32)edst[e] / (u32)BWID], 1);
  }
  __syncthreads();
  if (tid < NBUCK) atomicAdd(&bcnt[tid], hist[tid]);
}

// Exclusive scan of 256 bucket counts -> ebase (257 entries) and gcursor.
__global__ void k_bscan(const int* __restrict__ bcnt, int* __restrict__ ebase,
                        int* __restrict__ gcursor) {
  __shared__ int buf[NBUCK];
  int t = threadIdx.x;
  int v = bcnt[t];
  buf[t] = v;
  __syncthreads();
  for (int off = 1; off < NBUCK; off <<= 1) {
    int u = 0;
    if (t >= off) u = buf[t - off];
    __syncthreads();
    buf[t] += u;
    __syncthreads();
  }
  int ex = buf[t] - v;
  ebase[t] = ex;
  gcursor[t] = ex;
  if (t == NBUCK - 1) ebase[NBUCK] = buf[t];
}

// Pass 1 of multisplit: bucket-grouped append of (dst,src) pairs into ebuf.
__global__ __launch_bounds__(1024) void k_part(const int* __restrict__ esrc,
                                               const int* __restrict__ edst,
                                               int* __restrict__ gcursor,
                                               u64* __restrict__ ebuf) {
  __shared__ int hist[NBUCK];
  __shared__ int base[NBUCK];
  int tid = threadIdx.x;
  if (tid < NBUCK) hist[tid] = 0;
  __syncthreads();
  int e0 = blockIdx.x * 4096;
  int sv[4], dv[4], bk[4], rk[4];
  #pragma unroll
  for (int i = 0; i < 4; ++i) {
    int e = e0 + i * 1024 + tid;
    if (e < N_EDGES) {
      sv[i] = esrc[e];
      dv[i] = edst[e];
      bk[i] = (int)((u32)dv[i] / (u32)BWID);
      rk[i] = atomicAdd(&hist[bk[i]], 1);
    } else bk[i] = -1;
  }
  __syncthreads();
  if (tid < NBUCK) base[tid] = atomicAdd(&gcursor[tid], hist[tid]);
  __syncthreads();
  #pragma unroll
  for (int i = 0; i < 4; ++i) {
    if (bk[i] >= 0) {
      int pos = base[bk[i]] + rk[i];
      ebuf[pos] = ((u64)(u32)dv[i] << 32) | (u32)sv[i];
    }
  }
}

// Pass 2: one bucket per block. Count per-node in LDS, scan -> offs (coalesced
// write), then LDS-cursor scatter into the block-exclusive csr region.
__global__ __launch_bounds__(1024) void k_csr(const u64* __restrict__ ebuf,
                                              const int* __restrict__ ebase,
                                              int* __restrict__ offs,
                                              int* __restrict__ csr) {
  __shared__ int lcnt[512];
  __shared__ int lofs[512];
  int b = blockIdx.x, tid = threadIdx.x;
  int n0 = b * BWID;
  int n1 = min(n0 + BWID, N_NODES);
  int nn = n1 - n0;
  int e0 = ebase[b], e1 = ebase[b + 1];
  if (tid < 512) lcnt[tid] = 0;
  __syncthreads();
  for (int e = e0 + tid; e < e1; e += 1024) {
    int dst = (int)(ebuf[e] >> 32);
    atomicAdd(&lcnt[dst - n0], 1);
  }
  __syncthreads();
  if (tid < 512) lofs[tid] = lcnt[tid];
  __syncthreads();
  for (int off = 1; off < 512; off <<= 1) {
    int v = 0;
    if (tid < 512 && tid >= off) v = lofs[tid - off];
    __syncthreads();
    if (tid < 512 && tid >= off) lofs[tid] += v;
    __syncthreads();
  }
  int nodeoff = 0;
  if (tid < 512) nodeoff = e0 + lofs[tid] - lcnt[tid];  // exclusive
  if (tid < 512) lofs[tid] = nodeoff;                   // reuse as cursor
  if (tid < nn) offs[n0 + tid] = nodeoff;
  if (b == 0 && tid == 0) offs[N_NODES] = N_EDGES;
  __syncthreads();
  for (int e = e0 + tid; e < e1; e += 1024) {
    u64 p = ebuf[e];
    int src = (int)(p & 0xffffffffull);
    int dst = (int)(p >> 32);
    int pos = atomicAdd(&lofs[dst - n0], 1);
    csr[pos] = src;
  }
}

// ---------------- combined weight build ----------------
// Column-interleaved fragment order: per kc chunk (32 k), slot = wave*8 + u with
// u = gate*2 + hu; slot covers B column c = gate*128 + wave*32 + hu*16 + nl.
// Address: bsw[st][kc][slot][quad][nl][kl]  (quad=(k>>3)&3, kl=k&7).
// Wave w thus computes ALL FOUR gate values for its own 32 output columns.
__global__ void k_wb(const float* __restrict__ W, const float* __restrict__ w_ih,
                     const float* __restrict__ w_hh, u16* __restrict__ bsw) {
  __shared__ float wrow[128];
  int b = blockIdx.x, st = b >> 8, k = b & 255, t = threadIdx.x;
  if (k < 128) wrow[t] = W[(st * 128 + k) * 128 + t];
  __syncthreads();
  int kc = k >> 5, quad = (k >> 3) & 3, kl = k & 7;
  u16* base = bsw + (size_t)st * 131072 + kc * 16384;
  #pragma unroll
  for (int gq = 0; gq < 4; ++gq) {
    int c = gq * 128 + t;
    float v;
    if (k < 128) {
      if (c < 384) {
        const float* wr = w_ih + c * 128;
        float sacc = 0.f;
        for (int j = 0; j < 128; ++j) sacc += wrow[j] * wr[j];
        v = sacc;
      } else v = 0.f;
    } else {
      int kk = k - 128;
      if (c < 256)      v = w_hh[c * 128 + kk];
      else if (c < 384) v = 0.f;
      else              v = w_hh[(c - 128) * 128 + kk];
    }
    int gi = c >> 7, cw = c & 127;
    int wv = cw >> 5, hu = (cw >> 4) & 1, nl = c & 15;
    int slot = wv * 8 + gi * 2 + hu;
    base[(slot * 4 + quad) * 128 + nl * 8 + kl] = f2bf(v);
  }
}

// ---------------- x -> bf16 ----------------
__global__ void k_convert(const float* __restrict__ x, u16* __restrict__ h) {
  int i = (blockIdx.x * 256 + threadIdx.x) * 4;
  float4 v = *(const float4*)(x + i);
  u16 o[4] = {f2bf(v.x), f2bf(v.y), f2bf(v.z), f2bf(v.w)};
  *(uint2*)(h + i) = *(uint2*)o;
}

// ---------------- neighbor gather-sum: s[dst] = sum h[src] ----------------
__global__ void k_gather(const u16* __restrict__ h, const int* __restrict__ csr,
                         const int* __restrict__ offs, u16* __restrict__ s) {
  int node = blockIdx.x * 4 + (threadIdx.x >> 6);
  int lane = threadIdx.x & 63;
  int q   = lane >> 4;
  int sub = lane & 15;
  int beg = offs[node], end = offs[node + 1];
  float a0 = 0.f, a1 = 0.f, a2 = 0.f, a3 = 0.f;
  float a4 = 0.f, a5 = 0.f, a6 = 0.f, a7 = 0.f;
  for (int j = beg + q; j < end; j += 4) {
    int src = csr[j];
    uint4 p = *(const uint4*)(h + (size_t)src * 128 + sub * 8);
    a0 += bf2f((u16)(p.x & 0xffffu)); a1 += bf2f((u16)(p.x >> 16));
    a2 += bf2f((u16)(p.y & 0xffffu)); a3 += bf2f((u16)(p.y >> 16));
    a4 += bf2f((u16)(p.z & 0xffffu)); a5 += bf2f((u16)(p.z >> 16));
    a6 += bf2f((u16)(p.w & 0xffffu)); a7 += bf2f((u16)(p.w >> 16));
  }
  a0 += __shfl_xor(a0, 16); a0 += __shfl_xor(a0, 32);
  a1 += __shfl_xor(a1, 16); a1 += __shfl_xor(a1, 32);
  a2 += __shfl_xor(a2, 16); a2 += __shfl_xor(a2, 32);
  a3 += __shfl_xor(a3, 16); a3 += __shfl_xor(a3, 32);
  a4 += __shfl_xor(a4, 16); a4 += __shfl_xor(a4, 32);
  a5 += __shfl_xor(a5, 16); a5 += __shfl_xor(a5, 32);
  a6 += __shfl_xor(a6, 16); a6 += __shfl_xor(a6, 32);
  a7 += __shfl_xor(a7, 16); a7 += __shfl_xor(a7, 32);
  if (q == 0) {
    uint4 o;
    o.x = (u32)f2bf(a0) | ((u32)f2bf(a1) << 16);
    o.y = (u32)f2bf(a2) | ((u32)f2bf(a3) << 16);
    o.z = (u32)f2bf(a4) | ((u32)f2bf(a5) << 16);
    o.w = (u32)f2bf(a6) | ((u32)f2bf(a7) << 16);
    *(uint4*)(s + (size_t)node * 128 + sub * 8) = o;
  }
}

// ---------------- fused dual-GEMM + GRU cell ----------------
// 32 rows/block (3125 blocks), 4 waves. Wave w owns output cols w*32..w*32+31 and
// computes all 4 gates for them (column-interleaved B) -> GRU combine is pure
// register math, no gate LDS exchange. All wave64 frag reads are base+lane*16
// (conflict-free). Output staged through Bsw for coalesced uint4 stores.
__global__ __launch_bounds__(256) void k_gemm_gru(
    const u16* __restrict__ s_mat, const u16* __restrict__ h_mat,
    const u16* __restrict__ bsw, const float* __restrict__ b_ih,
    const float* __restrict__ b_hh, u16* __restrict__ h_out) {
  __shared__ u16 Asw[8192];    // 16 KB: A=[s|h], 32 rows x 256 k, [g][kslot][quad][nl][kl]
  __shared__ u16 Bsw[16384];   // 32 KB: one kc chunk of B; reused as out-stage [32][OUT_P]

  const int tid  = threadIdx.x;
  const int wave = tid >> 6;
  const int lane = tid & 63;
  const int nl   = lane & 15;
  const int quad = lane >> 4;
  const int row0 = blockIdx.x * 32;   // 3125 * 32 == 100000 exactly

  {  // stage A: thread (half, squad, snl) loads 4x16B; contiguous LDS writes per wave
    int snl = tid & 15, squad = (tid >> 4) & 3, sel = tid >> 6;
    int g = sel & 1, half = sel >> 1;             // g: 16-row group; half: 0=s, 1=h
    const u16* row = (half ? h_mat : s_mat) + (size_t)(row0 + g * 16 + snl) * 128;
    #pragma unroll
    for (int kc2 = 0; kc2 < 4; ++kc2) {
      uint4 v = *(const uint4*)(row + kc2 * 32 + squad * 8);
      *(uint4*)&Asw[(((g * 8 + half * 4 + kc2) * 4 + squad) * 16 + snl) * 8] = v;
    }
  }

  f32x4 acc[2][8];
  #pragma unroll
  for (int g = 0; g < 2; ++g)
    #pragma unroll
    for (int u = 0; u < 8; ++u) acc[g][u] = (f32x4){0.f, 0.f, 0.f, 0.f};

  for (int kc = 0; kc < 8; ++kc) {
    const u16* gsrc = bsw + kc * 16384;  // 32KB contiguous chunk, same layout as LDS
    #pragma unroll
    for (int i = 0; i < 8; ++i) {
      int inst = wave * 8 + i;
      gl_lds16(gsrc + inst * 512 + lane * 8, Bsw + inst * 512);
    }
    __syncthreads();
    bf16x8 a[2];
    a[0] = *(const bf16x8*)&Asw[kc * 512 + lane * 8];
    a[1] = *(const bf16x8*)&Asw[(8 + kc) * 512 + lane * 8];
    #pragma unroll
    for (int u = 0; u < 8; ++u) {
      bf16x8 bf = *(const bf16x8*)&Bsw[(wave * 8 + u) * 512 + lane * 8];
      acc[0][u] = __builtin_amdgcn_mfma_f32_16x16x32_bf16(a[0], bf, acc[0][u], 0, 0, 0);
      acc[1][u] = __builtin_amdgcn_mfma_f32_16x16x32_bf16(a[1], bf, acc[1][u], 0, 0, 0);
    }
    __syncthreads();
  }

  // biases: u = gate*2+hu, within-gate col cw = wave*32 + hu*16 + nl
  float bias[8];
  #pragma unroll
  for (int u = 0; u < 8; ++u) {
    int gi = u >> 1, hu = u & 1;
    int cw = wave * 32 + hu * 16 + nl;
    bias[u] = (gi == 0) ? b_ih[cw] + b_hh[cw]
            : (gi == 1) ? b_ih[128 + cw] + b_hh[128 + cw]
            : (gi == 2) ? b_ih[256 + cw]
                        : b_hh[256 + cw];
  }

  // register-resident GRU combine; results -> Bsw out-stage (safe: last K-loop
  // sync guarantees all frag reads of Bsw are done)
  #pragma unroll
  for (int g = 0; g < 2; ++g) {
    #pragma unroll
    for (int hu = 0; hu < 2; ++hu) {
      int cw = wave * 32 + hu * 16 + nl;     // output column
      // h value location in Asw: k = 128 + cw
      int hbase = ((g * 8 + 4 + wave) * 4 + ((hu * 2 + (nl >> 3)) & 3)) * 128 + (nl & 7);
      #pragma unroll
      for (int i = 0; i < 4; ++i) {
        int m = quad * 4 + i;                // row within 16-row group
        float rv = fast_sig(acc[g][0 + hu][i] + bias[0 + hu]);
        float zv = fast_sig(acc[g][2 + hu][i] + bias[2 + hu]);
        float iv = acc[g][4 + hu][i] + bias[4 + hu];
        float hn = acc[g][6 + hu][i] + bias[6 + hu];
        float hv = bf2f(Asw[hbase + m * 8]);
        float n  = fast_tanh(iv + rv * hn);
        float o  = (1.f - zv) * n + zv * hv;
        Bsw[(g * 16 + m) * OUT_P + cw] = f2bf(o);
      }
    }
  }
  __syncthreads();

  {  // coalesced store: 32 rows x 128 cols
    int r32 = tid >> 3, c0 = (tid & 7) * 16;
    uint4 v0 = *(const uint4*)&Bsw[r32 * OUT_P + c0];
    uint4 v1 = *(const uint4*)&Bsw[r32 * OUT_P + c0 + 8];
    uint4* dstp = (uint4*)(h_out + (size_t)(row0 + r32) * 128 + c0);
    dstp[0] = v0;
    dstp[1] = v1;
  }
}

// ---------------- relu + segment mean pool (two-phase, parallel) ----------------
__global__ void k_pool_partial(const u16* __restrict__ h, const int* __restrict__ batch,
                               float* __restrict__ acc) {
  int t = threadIdx.x;  // column 0..127
  int node0 = blockIdx.x * 125;
  int node1 = node0 + 125;
  int cur = batch[node0];
  float sum = 0.f;
  for (int r = node0; r < node1; ++r) {
    int g = batch[r];
    if (g != cur) {
      atomicAdd(&acc[cur * 128 + t], sum);
      sum = 0.f;
      cur = g;
    }
    sum += fmaxf(bf2f(h[(size_t)r * 128 + t]), 0.f);
  }
  atomicAdd(&acc[cur * 128 + t], sum);
}

__global__ void k_pool_div(const float* __restrict__ acc, const int* __restrict__ batch,
                           float* __restrict__ out) {
  __shared__ int se[2];
  int g = blockIdx.x, t = threadIdx.x;
  if (t < 2) {
    int target = g + t;
    int lo = 0, hi = N_NODES;
    while (lo < hi) { int mid = (lo + hi) >> 1; if (batch[mid] < target) lo = mid + 1; else hi = mid; }
    se[t] = lo;
  }
  __syncthreads();
  int cnt = se[1] - se[0];
  out[g * 128 + t] = acc[g * 128 + t] / (float)(cnt > 0 ? cnt : 1);
}

extern "C" void kernel_launch(void* const* d_in, const int* in_sizes, int n_in,
                              void* d_out, int out_size, void* d_ws, size_t ws_size,
                              hipStream_t stream) {
  const float* x     = (const float*)d_in[0];
  const int*   edges = (const int*)d_in[1];
  const int*   batch = (const int*)d_in[2];
  const float* W     = (const float*)d_in[3];
  const float* w_ih  = (const float*)d_in[4];
  const float* w_hh  = (const float*)d_in[5];
  const float* b_ih  = (const float*)d_in[6];
  const float* b_hh  = (const float*)d_in[7];
  float* out = (float*)d_out;

  char* w = (char*)d_ws;
  u16* buf0    = (u16*)(w);                 // 25,600,000 B  (h / s ping)
  u16* buf1    = (u16*)(w + 25600000);      // 25,600,000 B  (h / s pong)
  u16* bsw     = (u16*)(w + 51200000);      // 1,048,576 B
  float* acc   = (float*)(w + 52300032);    // 32,768 B  (pool accumulator)
  int* offs    = (int*)(w + 52710400);      // 400,004 B
  int* gcursor = (int*)(w + 53120768);      // 1,024 B
  int* bcnt    = (int*)(w + 53122048);      // 1,024 B
  int* ebase   = (int*)(w + 53123328);      // 1,028 B
  int* csr     = (int*)(w + 53531136);      // 6,400,000 B  -> total ~60 MB
  u64* ebuf    = (u64*)buf1;                // 12.8 MB; buf1 dead until 1st gather

  const int* esrc = edges;
  const int* edst = edges + N_EDGES;

  hipMemsetAsync(bcnt, 0, NBUCK * sizeof(int), stream);
  k_bhist<<<391, 1024, 0, stream>>>(edst, bcnt);
  k_bscan<<<1, NBUCK, 0, stream>>>(bcnt, ebase, gcursor);
  k_part<<<391, 1024, 0, stream>>>(esrc, edst, gcursor, ebuf);
  k_csr<<<NBUCK, 1024, 0, stream>>>(ebuf, ebase, offs, csr);
  k_wb<<<1024, 128, 0, stream>>>(W, w_ih, w_hh, bsw);
  k_convert<<<(N_NODES * HIDDEN) / 1024, 256, 0, stream>>>(x, buf0);
  hipMemsetAsync(acc, 0, N_GRAPHS * HIDDEN * sizeof(float), stream);

  u16* hcur = buf0;
  u16* hnxt = buf1;
  for (int st = 0; st < STEPS; ++st) {
    k_gather<<<N_NODES / 4, 256, 0, stream>>>(hcur, csr, offs, hnxt);
    // in-place: each block reads only its own 32 rows of s (hnxt) and h (hcur)
    // into LDS before writing h_out (hnxt) over those same rows.
    k_gemm_gru<<<N_NODES / 32, 256, 0, stream>>>(hnxt, hcur, bsw + st * 131072,
                                                 b_ih, b_hh, hnxt);
    u16* tmp = hcur; hcur = hnxt; hnxt = tmp;
  }
  k_pool_partial<<<800, 128, 0, stream>>>(hcur, batch, acc);
  k_pool_div<<<N_GRAPHS, 128, 0, stream>>>(acc, batch, out);
}

// Round 8
// 665.147 us; speedup vs baseline: 1.5296x; 1.0500x over previous
//
#include <hip/hip_runtime.h>

#define N_NODES  100000
#define N_EDGES  1600000
#define HIDDEN   128
#define STEPS    4
#define N_GRAPHS 64
#define NBUCK    256
#define BWID     391   // nodes per bucket: 256*391 = 100096 >= 100000
#define OUT_P    136   // output-staging row pitch (u16)

typedef unsigned short u16;
typedef unsigned int   u32;
typedef unsigned long long u64;
typedef __attribute__((ext_vector_type(8))) short bf16x8;
typedef __attribute__((ext_vector_type(4))) float f32x4;

__device__ inline u16 f2bf(float f) {
  u32 u = __float_as_uint(f);
  u = (u + 0x7FFFu + ((u >> 16) & 1u)) >> 16;  // RTNE
  return (u16)u;
}
__device__ inline float bf2f(u16 b) { return __uint_as_float(((u32)b) << 16); }

__device__ inline float fast_sig(float x) { return 1.f / (1.f + __expf(-x)); }
__device__ inline float fast_tanh(float x) {
  x = fminf(fmaxf(x, -15.f), 15.f);
  float e = __expf(2.f * x);
  return (e - 1.f) / (e + 1.f);
}

// ---------------- CSR build (bucketed, no global per-node atomics) ----------------
__global__ __launch_bounds__(1024) void k_bhist(const int* __restrict__ edst,
                                                int* __restrict__ bcnt) {
  __shared__ int hist[NBUCK];
  int tid = threadIdx.x;
  if (tid < NBUCK) hist[tid] = 0;
  __syncthreads();
  int e0 = blockIdx.x * 4096;
  #pragma unroll
  for (int i = 0; i < 4; ++i) {
    int e = e0 + i * 1024 + tid;
    if (e < N_EDGES) atomicAdd(&hist[(u32)edst[e] / (u32)BWID], 1);
  }
  __syncthreads();
  if (tid < NBUCK) atomicAdd(&bcnt[tid], hist[tid]);
}

__global__ void k_bscan(const int* __restrict__ bcnt, int* __restrict__ ebase,
                        int* __restrict__ gcursor) {
  __shared__ int buf[NBUCK];
  int t = threadIdx.x;
  int v = bcnt[t];
  buf[t] = v;
  __syncthreads();
  for (int off = 1; off < NBUCK; off <<= 1) {
    int u = 0;
    if (t >= off) u = buf[t - off];
    __syncthreads();
    buf[t] += u;
    __syncthreads();
  }
  int ex = buf[t] - v;
  ebase[t] = ex;
  gcursor[t] = ex;
  if (t == NBUCK - 1) ebase[NBUCK] = buf[t];
}

__global__ __launch_bounds__(1024) void k_part(const int* __restrict__ esrc,
                                               const int* __restrict__ edst,
                                               int* __restrict__ gcursor,
                                               u64* __restrict__ ebuf) {
  __shared__ int hist[NBUCK];
  __shared__ int base[NBUCK];
  int tid = threadIdx.x;
  if (tid < NBUCK) hist[tid] = 0;
  __syncthreads();
  int e0 = blockIdx.x * 4096;
  int sv[4], dv[4], bk[4], rk[4];
  #pragma unroll
  for (int i = 0; i < 4; ++i) {
    int e = e0 + i * 1024 + tid;
    if (e < N_EDGES) {
      sv[i] = esrc[e];
      dv[i] = edst[e];
      bk[i] = (int)((u32)dv[i] / (u32)BWID);
      rk[i] = atomicAdd(&hist[bk[i]], 1);
    } else bk[i] = -1;
  }
  __syncthreads();
  if (tid < NBUCK) base[tid] = atomicAdd(&gcursor[tid], hist[tid]);
  __syncthreads();
  #pragma unroll
  for (int i = 0; i < 4; ++i) {
    if (bk[i] >= 0) {
      int pos = base[bk[i]] + rk[i];
      ebuf[pos] = ((u64)(u32)dv[i] << 32) | (u32)sv[i];
    }
  }
}

__global__ __launch_bounds__(1024) void k_csr(const u64* __restrict__ ebuf,
                                              const int* __restrict__ ebase,
                                              int* __restrict__ offs,
                                              int* __restrict__ csr) {
  __shared__ int lcnt[512];
  __shared__ int lofs[512];
  int b = blockIdx.x, tid = threadIdx.x;
  int n0 = b * BWID;
  int n1 = min(n0 + BWID, N_NODES);
  int nn = n1 - n0;
  int e0 = ebase[b], e1 = ebase[b + 1];
  if (tid < 512) lcnt[tid] = 0;
  __syncthreads();
  for (int e = e0 + tid; e < e1; e += 1024) {
    int dst = (int)(ebuf[e] >> 32);
    atomicAdd(&lcnt[dst - n0], 1);
  }
  __syncthreads();
  if (tid < 512) lofs[tid] = lcnt[tid];
  __syncthreads();
  for (int off = 1; off < 512; off <<= 1) {
    int v = 0;
    if (tid < 512 && tid >= off) v = lofs[tid - off];
    __syncthreads();
    if (tid < 512 && tid >= off) lofs[tid] += v;
    __syncthreads();
  }
  int nodeoff = 0;
  if (tid < 512) nodeoff = e0 + lofs[tid] - lcnt[tid];  // exclusive
  if (tid < 512) lofs[tid] = nodeoff;                   // reuse as cursor
  if (tid < nn) offs[n0 + tid] = nodeoff;
  if (b == 0 && tid == 0) offs[N_NODES] = N_EDGES;
  __syncthreads();
  for (int e = e0 + tid; e < e1; e += 1024) {
    u64 p = ebuf[e];
    int src = (int)(p & 0xffffffffull);
    int dst = (int)(p >> 32);
    int pos = atomicAdd(&lofs[dst - n0], 1);
    csr[pos] = src;
  }
}

// ---------------- combined weight build ----------------
// Column-interleaved fragment order: per kc chunk (32 k), slot = wave*8 + u with
// u = gate*2 + hu; slot covers B column c = gate*128 + wave*32 + hu*16 + nl.
// Address: bsw[st][kc][slot][quad][nl][kl]  (quad=(k>>3)&3, kl=k&7).
__global__ void k_wb(const float* __restrict__ W, const float* __restrict__ w_ih,
                     const float* __restrict__ w_hh, u16* __restrict__ bsw) {
  __shared__ float wrow[128];
  int b = blockIdx.x, st = b >> 8, k = b & 255, t = threadIdx.x;
  if (k < 128) wrow[t] = W[(st * 128 + k) * 128 + t];
  __syncthreads();
  int kc = k >> 5, quad = (k >> 3) & 3, kl = k & 7;
  u16* base = bsw + (size_t)st * 131072 + kc * 16384;
  #pragma unroll
  for (int gq = 0; gq < 4; ++gq) {
    int c = gq * 128 + t;
    float v;
    if (k < 128) {
      if (c < 384) {
        const float* wr = w_ih + c * 128;
        float sacc = 0.f;
        for (int j = 0; j < 128; ++j) sacc += wrow[j] * wr[j];
        v = sacc;
      } else v = 0.f;
    } else {
      int kk = k - 128;
      if (c < 256)      v = w_hh[c * 128 + kk];
      else if (c < 384) v = 0.f;
      else              v = w_hh[(c - 128) * 128 + kk];
    }
    int gi = c >> 7, cw = c & 127;
    int wv = cw >> 5, hu = (cw >> 4) & 1, nl = c & 15;
    int slot = wv * 8 + gi * 2 + hu;
    base[(slot * 4 + quad) * 128 + nl * 8 + kl] = f2bf(v);
  }
}

// ---------------- x -> bf16 ----------------
__global__ void k_convert(const float* __restrict__ x, u16* __restrict__ h) {
  int i = (blockIdx.x * 256 + threadIdx.x) * 4;
  float4 v = *(const float4*)(x + i);
  u16 o[4] = {f2bf(v.x), f2bf(v.y), f2bf(v.z), f2bf(v.w)};
  *(uint2*)(h + i) = *(uint2*)o;
}

// ---------------- neighbor gather-sum: s[dst] = sum h[src] ----------------
__global__ void k_gather(const u16* __restrict__ h, const int* __restrict__ csr,
                         const int* __restrict__ offs, u16* __restrict__ s) {
  int node = blockIdx.x * 4 + (threadIdx.x >> 6);
  int lane = threadIdx.x & 63;
  int q   = lane >> 4;
  int sub = lane & 15;
  int beg = offs[node], end = offs[node + 1];
  float a0 = 0.f, a1 = 0.f, a2 = 0.f, a3 = 0.f;
  float a4 = 0.f, a5 = 0.f, a6 = 0.f, a7 = 0.f;
  for (int j = beg + q; j < end; j += 4) {
    int src = csr[j];
    uint4 p = *(const uint4*)(h + (size_t)src * 128 + sub * 8);
    a0 += bf2f((u16)(p.x & 0xffffu)); a1 += bf2f((u16)(p.x >> 16));
    a2 += bf2f((u16)(p.y & 0xffffu)); a3 += bf2f((u16)(p.y >> 16));
    a4 += bf2f((u16)(p.z & 0xffffu)); a5 += bf2f((u16)(p.z >> 16));
    a6 += bf2f((u16)(p.w & 0xffffu)); a7 += bf2f((u16)(p.w >> 16));
  }
  a0 += __shfl_xor(a0, 16); a0 += __shfl_xor(a0, 32);
  a1 += __shfl_xor(a1, 16); a1 += __shfl_xor(a1, 32);
  a2 += __shfl_xor(a2, 16); a2 += __shfl_xor(a2, 32);
  a3 += __shfl_xor(a3, 16); a3 += __shfl_xor(a3, 32);
  a4 += __shfl_xor(a4, 16); a4 += __shfl_xor(a4, 32);
  a5 += __shfl_xor(a5, 16); a5 += __shfl_xor(a5, 32);
  a6 += __shfl_xor(a6, 16); a6 += __shfl_xor(a6, 32);
  a7 += __shfl_xor(a7, 16); a7 += __shfl_xor(a7, 32);
  if (q == 0) {
    uint4 o;
    o.x = (u32)f2bf(a0) | ((u32)f2bf(a1) << 16);
    o.y = (u32)f2bf(a2) | ((u32)f2bf(a3) << 16);
    o.z = (u32)f2bf(a4) | ((u32)f2bf(a5) << 16);
    o.w = (u32)f2bf(a6) | ((u32)f2bf(a7) << 16);
    *(uint4*)(s + (size_t)node * 128 + sub * 8) = o;
  }
}

// ---------------- fused dual-GEMM + GRU cell ----------------
// 32 rows/block, 4 waves, wave w owns output cols w*32..+31 (all 4 gates).
// B fragments are loaded DIRECTLY global->VGPR (L2-resident, frag-ordered,
// wave-private) with one-kc-ahead double buffering -> the K-loop has NO
// __syncthreads() and no global_load_lds vmcnt(0) drains.
// Structural zeros skipped: i_n slots (u=4,5) only kc<4; h_n (u=6,7) only kc>=4.
__global__ __launch_bounds__(256, 3) void k_gemm_gru(
    const u16* __restrict__ s_mat, const u16* __restrict__ h_mat,
    const u16* __restrict__ bsw, const float* __restrict__ b_ih,
    const float* __restrict__ b_hh, u16* __restrict__ h_out) {
  __shared__ u16 Asw[8192];       // 16 KB: A=[s|h], 32 rows x 256 k, frag-ordered
  __shared__ u16 Osw[32 * OUT_P]; // 8.7 KB out-stage

  const int tid  = threadIdx.x;
  const int wave = tid >> 6;
  const int lane = tid & 63;
  const int nl   = lane & 15;
  const int quad = lane >> 4;
  const int row0 = blockIdx.x * 32;   // 3125 * 32 == 100000 exactly

  {  // stage A: thread (half, squad, snl) loads 4x16B; contiguous LDS writes per wave
    int snl = tid & 15, squad = (tid >> 4) & 3, sel = tid >> 6;
    int g = sel & 1, half = sel >> 1;             // g: 16-row group; half: 0=s, 1=h
    const u16* row = (half ? h_mat : s_mat) + (size_t)(row0 + g * 16 + snl) * 128;
    #pragma unroll
    for (int kc2 = 0; kc2 < 4; ++kc2) {
      uint4 v = *(const uint4*)(row + kc2 * 32 + squad * 8);
      *(uint4*)&Asw[(((g * 8 + half * 4 + kc2) * 4 + squad) * 16 + snl) * 8] = v;
    }
  }
  __syncthreads();

  // wave-private B fragment base (u16 units); slot u at +u*512, kc at +kc*16384
  const u16* bp = bsw + wave * 8 * 512 + lane * 8;

  f32x4 acc[2][8];
  #pragma unroll
  for (int g = 0; g < 2; ++g)
    #pragma unroll
    for (int u = 0; u < 8; ++u) acc[g][u] = (f32x4){0.f, 0.f, 0.f, 0.f};

  // active slot sets: kc<4 -> {0,1,2,3,4,5} (r,z,i_n); kc>=4 -> {0,1,2,3,6,7} (r,z,h_n)
  bf16x8 bcur[6], bnext[6];
  #pragma unroll
  for (int i = 0; i < 6; ++i) bcur[i] = *(const bf16x8*)(bp + i * 512);

  #pragma unroll
  for (int kc = 0; kc < 8; ++kc) {
    if (kc < 7) {
      #pragma unroll
      for (int i = 0; i < 6; ++i) {
        int us = (kc + 1 < 4) ? i : (i < 4 ? i : i + 2);
        bnext[i] = *(const bf16x8*)(bp + (kc + 1) * 16384 + us * 512);
      }
    }
    bf16x8 a0 = *(const bf16x8*)&Asw[kc * 512 + lane * 8];
    bf16x8 a1 = *(const bf16x8*)&Asw[(8 + kc) * 512 + lane * 8];
    #pragma unroll
    for (int i = 0; i < 6; ++i) {
      int u = (kc < 4) ? i : (i < 4 ? i : i + 2);
      acc[0][u] = __builtin_amdgcn_mfma_f32_16x16x32_bf16(a0, bcur[i], acc[0][u], 0, 0, 0);
      acc[1][u] = __builtin_amdgcn_mfma_f32_16x16x32_bf16(a1, bcur[i], acc[1][u], 0, 0, 0);
    }
    #pragma unroll
    for (int i = 0; i < 6; ++i) bcur[i] = bnext[i];
  }

  // biases: u = gate*2+hu, within-gate col cw = wave*32 + hu*16 + nl
  float bias[8];
  #pragma unroll
  for (int u = 0; u < 8; ++u) {
    int gi = u >> 1, hu = u & 1;
    int cw = wave * 32 + hu * 16 + nl;
    bias[u] = (gi == 0) ? b_ih[cw] + b_hh[cw]
            : (gi == 1) ? b_ih[128 + cw] + b_hh[128 + cw]
            : (gi == 2) ? b_ih[256 + cw]
                        : b_hh[256 + cw];
  }

  // register-resident GRU combine; results -> Osw out-stage
  #pragma unroll
  for (int g = 0; g < 2; ++g) {
    #pragma unroll
    for (int hu = 0; hu < 2; ++hu) {
      int cw = wave * 32 + hu * 16 + nl;     // output column
      int hbase = ((g * 8 + 4 + wave) * 4 + ((hu * 2 + (nl >> 3)) & 3)) * 128 + (nl & 7);
      #pragma unroll
      for (int i = 0; i < 4; ++i) {
        int m = quad * 4 + i;                // row within 16-row group
        float rv = fast_sig(acc[g][0 + hu][i] + bias[0 + hu]);
        float zv = fast_sig(acc[g][2 + hu][i] + bias[2 + hu]);
        float iv = acc[g][4 + hu][i] + bias[4 + hu];
        float hn = acc[g][6 + hu][i] + bias[6 + hu];
        float hv = bf2f(Asw[hbase + m * 8]);
        float n  = fast_tanh(iv + rv * hn);
        float o  = (1.f - zv) * n + zv * hv;
        Osw[(g * 16 + m) * OUT_P + cw] = f2bf(o);
      }
    }
  }
  __syncthreads();

  {  // coalesced store: 32 rows x 128 cols
    int r32 = tid >> 3, c0 = (tid & 7) * 16;
    uint4 v0 = *(const uint4*)&Osw[r32 * OUT_P + c0];
    uint4 v1 = *(const uint4*)&Osw[r32 * OUT_P + c0 + 8];
    uint4* dstp = (uint4*)(h_out + (size_t)(row0 + r32) * 128 + c0);
    dstp[0] = v0;
    dstp[1] = v1;
  }
}

// ---------------- relu + segment mean pool (two-phase, parallel) ----------------
__global__ void k_pool_partial(const u16* __restrict__ h, const int* __restrict__ batch,
                               float* __restrict__ acc) {
  int t = threadIdx.x;  // column 0..127
  int node0 = blockIdx.x * 125;
  int node1 = node0 + 125;
  int cur = batch[node0];
  float sum = 0.f;
  for (int r = node0; r < node1; ++r) {
    int g = batch[r];
    if (g != cur) {
      atomicAdd(&acc[cur * 128 + t], sum);
      sum = 0.f;
      cur = g;
    }
    sum += fmaxf(bf2f(h[(size_t)r * 128 + t]), 0.f);
  }
  atomicAdd(&acc[cur * 128 + t], sum);
}

__global__ void k_pool_div(const float* __restrict__ acc, const int* __restrict__ batch,
                           float* __restrict__ out) {
  __shared__ int se[2];
  int g = blockIdx.x, t = threadIdx.x;
  if (t < 2) {
    int target = g + t;
    int lo = 0, hi = N_NODES;
    while (lo < hi) { int mid = (lo + hi) >> 1; if (batch[mid] < target) lo = mid + 1; else hi = mid; }
    se[t] = lo;
  }
  __syncthreads();
  int cnt = se[1] - se[0];
  out[g * 128 + t] = acc[g * 128 + t] / (float)(cnt > 0 ? cnt : 1);
}

extern "C" void kernel_launch(void* const* d_in, const int* in_sizes, int n_in,
                              void* d_out, int out_size, void* d_ws, size_t ws_size,
                              hipStream_t stream) {
  const float* x     = (const float*)d_in[0];
  const int*   edges = (const int*)d_in[1];
  const int*   batch = (const int*)d_in[2];
  const float* W     = (const float*)d_in[3];
  const float* w_ih  = (const float*)d_in[4];
  const float* w_hh  = (const float*)d_in[5];
  const float* b_ih  = (const float*)d_in[6];
  const float* b_hh  = (const float*)d_in[7];
  float* out = (float*)d_out;

  char* w = (char*)d_ws;
  u16* buf0    = (u16*)(w);                 // 25,600,000 B  (h / s ping)
  u16* buf1    = (u16*)(w + 25600000);      // 25,600,000 B  (h / s pong)
  u16* bsw     = (u16*)(w + 51200000);      // 1,048,576 B
  float* acc   = (float*)(w + 52300032);    // 32,768 B  (pool accumulator)
  int* offs    = (int*)(w + 52710400);      // 400,004 B
  int* gcursor = (int*)(w + 53120768);      // 1,024 B
  int* bcnt    = (int*)(w + 53122048);      // 1,024 B
  int* ebase   = (int*)(w + 53123328);      // 1,028 B
  int* csr     = (int*)(w + 53531136);      // 6,400,000 B  -> total ~60 MB
  u64* ebuf    = (u64*)buf1;                // 12.8 MB; buf1 dead until 1st gather

  const int* esrc = edges;
  const int* edst = edges + N_EDGES;

  hipMemsetAsync(bcnt, 0, NBUCK * sizeof(int), stream);
  k_bhist<<<391, 1024, 0, stream>>>(edst, bcnt);
  k_bscan<<<1, NBUCK, 0, stream>>>(bcnt, ebase, gcursor);
  k_part<<<391, 1024, 0, stream>>>(esrc, edst, gcursor, ebuf);
  k_csr<<<NBUCK, 1024, 0, stream>>>(ebuf, ebase, offs, csr);
  k_wb<<<1024, 128, 0, stream>>>(W, w_ih, w_hh, bsw);
  k_convert<<<(N_NODES * HIDDEN) / 1024, 256, 0, stream>>>(x, buf0);
  hipMemsetAsync(acc, 0, N_GRAPHS * HIDDEN * sizeof(float), stream);

  u16* hcur = buf0;
  u16* hnxt = buf1;
  for (int st = 0; st < STEPS; ++st) {
    k_gather<<<N_NODES / 4, 256, 0, stream>>>(hcur, csr, offs, hnxt);
    // in-place: each block reads only its own 32 rows of s (hnxt) and h (hcur)
    // into LDS before writing h_out (hnxt) over those same rows.
    k_gemm_gru<<<N_NODES / 32, 256, 0, stream>>>(hnxt, hcur, bsw + st * 131072,
                                                 b_ih, b_hh, hnxt);
    u16* tmp = hcur; hcur = hnxt; hnxt = tmp;
  }
  k_pool_partial<<<800, 128, 0, stream>>>(hcur, batch, acc);
  k_pool_div<<<N_GRAPHS, 128, 0, stream>>>(acc, batch, out);
}

// Round 9
// 642.926 us; speedup vs baseline: 1.5825x; 1.0346x over previous
//
#include <hip/hip_runtime.h>

#define N_NODES  100000
#define N_EDGES  1600000
#define HIDDEN   128
#define STEPS    4
#define N_GRAPHS 64
#define NBUCK    256
#define BWID     391   // nodes per bucket: 256*391 = 100096 >= 100000
#define OUT_P    136   // output-staging row pitch (u16)

typedef unsigned short u16;
typedef unsigned int   u32;
typedef unsigned long long u64;
typedef __attribute__((ext_vector_type(8))) short bf16x8;
typedef __attribute__((ext_vector_type(4))) float f32x4;

__device__ inline u16 f2bf(float f) {
  u32 u = __float_as_uint(f);
  u = (u + 0x7FFFu + ((u >> 16) & 1u)) >> 16;  // RTNE
  return (u16)u;
}
__device__ inline float bf2f(u16 b) { return __uint_as_float(((u32)b) << 16); }

__device__ inline float fast_sig(float x) { return 1.f / (1.f + __expf(-x)); }
__device__ inline float fast_tanh(float x) {
  x = fminf(fmaxf(x, -15.f), 15.f);
  float e = __expf(2.f * x);
  return (e - 1.f) / (e + 1.f);
}

// ---------------- CSR build (bucketed, no global per-node atomics) ----------------
__global__ __launch_bounds__(1024) void k_bhist(const int* __restrict__ edst,
                                                int* __restrict__ bcnt) {
  __shared__ int hist[NBUCK];
  int tid = threadIdx.x;
  if (tid < NBUCK) hist[tid] = 0;
  __syncthreads();
  int e0 = blockIdx.x * 4096;
  #pragma unroll
  for (int i = 0; i < 4; ++i) {
    int e = e0 + i * 1024 + tid;
    if (e < N_EDGES) atomicAdd(&hist[(u32)edst[e] / (u32)BWID], 1);
  }
  __syncthreads();
  if (tid < NBUCK) atomicAdd(&bcnt[tid], hist[tid]);
}

__global__ void k_bscan(const int* __restrict__ bcnt, int* __restrict__ ebase,
                        int* __restrict__ gcursor) {
  __shared__ int buf[NBUCK];
  int t = threadIdx.x;
  int v = bcnt[t];
  buf[t] = v;
  __syncthreads();
  for (int off = 1; off < NBUCK; off <<= 1) {
    int u = 0;
    if (t >= off) u = buf[t - off];
    __syncthreads();
    buf[t] += u;
    __syncthreads();
  }
  int ex = buf[t] - v;
  ebase[t] = ex;
  gcursor[t] = ex;
  if (t == NBUCK - 1) ebase[NBUCK] = buf[t];
}

__global__ __launch_bounds__(1024) void k_part(const int* __restrict__ esrc,
                                               const int* __restrict__ edst,
                                               int* __restrict__ gcursor,
                                               u64* __restrict__ ebuf) {
  __shared__ int hist[NBUCK];
  __shared__ int base[NBUCK];
  int tid = threadIdx.x;
  if (tid < NBUCK) hist[tid] = 0;
  __syncthreads();
  int e0 = blockIdx.x * 4096;
  int sv[4], dv[4], bk[4], rk[4];
  #pragma unroll
  for (int i = 0; i < 4; ++i) {
    int e = e0 + i * 1024 + tid;
    if (e < N_EDGES) {
      sv[i] = esrc[e];
      dv[i] = edst[e];
      bk[i] = (int)((u32)dv[i] / (u32)BWID);
      rk[i] = atomicAdd(&hist[bk[i]], 1);
    } else bk[i] = -1;
  }
  __syncthreads();
  if (tid < NBUCK) base[tid] = atomicAdd(&gcursor[tid], hist[tid]);
  __syncthreads();
  #pragma unroll
  for (int i = 0; i < 4; ++i) {
    if (bk[i] >= 0) {
      int pos = base[bk[i]] + rk[i];
      ebuf[pos] = ((u64)(u32)dv[i] << 32) | (u32)sv[i];
    }
  }
}

__global__ __launch_bounds__(1024) void k_csr(const u64* __restrict__ ebuf,
                                              const int* __restrict__ ebase,
                                              int* __restrict__ offs,
                                              int* __restrict__ csr) {
  __shared__ int lcnt[512];
  __shared__ int lofs[512];
  int b = blockIdx.x, tid = threadIdx.x;
  int n0 = b * BWID;
  int n1 = min(n0 + BWID, N_NODES);
  int nn = n1 - n0;
  int e0 = ebase[b], e1 = ebase[b + 1];
  if (tid < 512) lcnt[tid] = 0;
  __syncthreads();
  for (int e = e0 + tid; e < e1; e += 1024) {
    int dst = (int)(ebuf[e] >> 32);
    atomicAdd(&lcnt[dst - n0], 1);
  }
  __syncthreads();
  if (tid < 512) lofs[tid] = lcnt[tid];
  __syncthreads();
  for (int off = 1; off < 512; off <<= 1) {
    int v = 0;
    if (tid < 512 && tid >= off) v = lofs[tid - off];
    __syncthreads();
    if (tid < 512 && tid >= off) lofs[tid] += v;
    __syncthreads();
  }
  int nodeoff = 0;
  if (tid < 512) nodeoff = e0 + lofs[tid] - lcnt[tid];  // exclusive
  if (tid < 512) lofs[tid] = nodeoff;                   // reuse as cursor
  if (tid < nn) offs[n0 + tid] = nodeoff;
  if (b == 0 && tid == 0) offs[N_NODES] = N_EDGES;
  __syncthreads();
  for (int e = e0 + tid; e < e1; e += 1024) {
    u64 p = ebuf[e];
    int src = (int)(p & 0xffffffffull);
    int dst = (int)(p >> 32);
    int pos = atomicAdd(&lofs[dst - n0], 1);
    csr[pos] = src;
  }
}

// ---------------- combined weight build ----------------
// Column-interleaved fragment order: per kc chunk (32 k), slot = wave*8 + u with
// u = gate*2 + hu; slot covers B column c = gate*128 + wave*32 + hu*16 + nl.
// Address: bsw[st][kc][slot][quad][nl][kl]  (quad=(k>>3)&3, kl=k&7).
__global__ void k_wb(const float* __restrict__ W, const float* __restrict__ w_ih,
                     const float* __restrict__ w_hh, u16* __restrict__ bsw) {
  __shared__ float wrow[128];
  int b = blockIdx.x, st = b >> 8, k = b & 255, t = threadIdx.x;
  if (k < 128) wrow[t] = W[(st * 128 + k) * 128 + t];
  __syncthreads();
  int kc = k >> 5, quad = (k >> 3) & 3, kl = k & 7;
  u16* base = bsw + (size_t)st * 131072 + kc * 16384;
  #pragma unroll
  for (int gq = 0; gq < 4; ++gq) {
    int c = gq * 128 + t;
    float v;
    if (k < 128) {
      if (c < 384) {
        const float* wr = w_ih + c * 128;
        float sacc = 0.f;
        for (int j = 0; j < 128; ++j) sacc += wrow[j] * wr[j];
        v = sacc;
      } else v = 0.f;
    } else {
      int kk = k - 128;
      if (c < 256)      v = w_hh[c * 128 + kk];
      else if (c < 384) v = 0.f;
      else              v = w_hh[(c - 128) * 128 + kk];
    }
    int gi = c >> 7, cw = c & 127;
    int wv = cw >> 5, hu = (cw >> 4) & 1, nl = c & 15;
    int slot = wv * 8 + gi * 2 + hu;
    base[(slot * 4 + quad) * 128 + nl * 8 + kl] = f2bf(v);
  }
}

// ---------------- x -> bf16 ----------------
__global__ void k_convert(const float* __restrict__ x, u16* __restrict__ h) {
  int i = (blockIdx.x * 256 + threadIdx.x) * 4;
  float4 v = *(const float4*)(x + i);
  u16 o[4] = {f2bf(v.x), f2bf(v.y), f2bf(v.z), f2bf(v.w)};
  *(uint2*)(h + i) = *(uint2*)o;
}

// ---------------- neighbor gather-sum: s[dst] = sum h[src] ----------------
// One node per wave; quarter-wave q takes edges j = beg+q+4t. 4-deep software
// pipeline: 4 csr reads + 4 independent 16B row loads in flight before any
// accumulation -> hides L2/LLC latency.
__device__ inline void acc8(float* a, uint4 p) {
  a[0] += bf2f((u16)(p.x & 0xffffu)); a[1] += bf2f((u16)(p.x >> 16));
  a[2] += bf2f((u16)(p.y & 0xffffu)); a[3] += bf2f((u16)(p.y >> 16));
  a[4] += bf2f((u16)(p.z & 0xffffu)); a[5] += bf2f((u16)(p.z >> 16));
  a[6] += bf2f((u16)(p.w & 0xffffu)); a[7] += bf2f((u16)(p.w >> 16));
}

__global__ void k_gather(const u16* __restrict__ h, const int* __restrict__ csr,
                         const int* __restrict__ offs, u16* __restrict__ s) {
  int node = blockIdx.x * 4 + (threadIdx.x >> 6);
  int lane = threadIdx.x & 63;
  int q   = lane >> 4;
  int sub = lane & 15;
  int beg = offs[node], end = offs[node + 1];
  float a[8] = {0.f, 0.f, 0.f, 0.f, 0.f, 0.f, 0.f, 0.f};
  int j = beg + q;
  for (; j + 12 < end; j += 16) {
    int s0 = csr[j], s1 = csr[j + 4], s2 = csr[j + 8], s3 = csr[j + 12];
    uint4 p0 = *(const uint4*)(h + (size_t)s0 * 128 + sub * 8);
    uint4 p1 = *(const uint4*)(h + (size_t)s1 * 128 + sub * 8);
    uint4 p2 = *(const uint4*)(h + (size_t)s2 * 128 + sub * 8);
    uint4 p3 = *(const uint4*)(h + (size_t)s3 * 128 + sub * 8);
    acc8(a, p0); acc8(a, p1); acc8(a, p2); acc8(a, p3);
  }
  for (; j < end; j += 4) {
    int s0 = csr[j];
    uint4 p0 = *(const uint4*)(h + (size_t)s0 * 128 + sub * 8);
    acc8(a, p0);
  }
  #pragma unroll
  for (int i = 0; i < 8; ++i) {
    a[i] += __shfl_xor(a[i], 16);
    a[i] += __shfl_xor(a[i], 32);
  }
  if (q == 0) {
    uint4 o;
    o.x = (u32)f2bf(a[0]) | ((u32)f2bf(a[1]) << 16);
    o.y = (u32)f2bf(a[2]) | ((u32)f2bf(a[3]) << 16);
    o.z = (u32)f2bf(a[4]) | ((u32)f2bf(a[5]) << 16);
    o.w = (u32)f2bf(a[6]) | ((u32)f2bf(a[7]) << 16);
    *(uint4*)(s + (size_t)node * 128 + sub * 8) = o;
  }
}

// ---------------- fused dual-GEMM + GRU cell ----------------
// 32 rows/block, 4 waves, wave w owns output cols w*32..+31 (all 4 gates).
// B fragments are loaded DIRECTLY global->VGPR (L2-resident, frag-ordered,
// wave-private) with one-kc-ahead double buffering -> the K-loop has NO
// __syncthreads() and no global_load_lds vmcnt(0) drains.
// Structural zeros skipped: i_n slots (u=4,5) only kc<4; h_n (u=6,7) only kc>=4.
__global__ __launch_bounds__(256, 3) void k_gemm_gru(
    const u16* __restrict__ s_mat, const u16* __restrict__ h_mat,
    const u16* __restrict__ bsw, const float* __restrict__ b_ih,
    const float* __restrict__ b_hh, u16* __restrict__ h_out) {
  __shared__ u16 Asw[8192];       // 16 KB: A=[s|h], 32 rows x 256 k, frag-ordered
  __shared__ u16 Osw[32 * OUT_P]; // 8.7 KB out-stage

  const int tid  = threadIdx.x;
  const int wave = tid >> 6;
  const int lane = tid & 63;
  const int nl   = lane & 15;
  const int quad = lane >> 4;
  const int row0 = blockIdx.x * 32;   // 3125 * 32 == 100000 exactly

  {  // stage A: thread (half, squad, snl) loads 4x16B; contiguous LDS writes per wave
    int snl = tid & 15, squad = (tid >> 4) & 3, sel = tid >> 6;
    int g = sel & 1, half = sel >> 1;             // g: 16-row group; half: 0=s, 1=h
    const u16* row = (half ? h_mat : s_mat) + (size_t)(row0 + g * 16 + snl) * 128;
    #pragma unroll
    for (int kc2 = 0; kc2 < 4; ++kc2) {
      uint4 v = *(const uint4*)(row + kc2 * 32 + squad * 8);
      *(uint4*)&Asw[(((g * 8 + half * 4 + kc2) * 4 + squad) * 16 + snl) * 8] = v;
    }
  }
  __syncthreads();

  // wave-private B fragment base (u16 units); slot u at +u*512, kc at +kc*16384
  const u16* bp = bsw + wave * 8 * 512 + lane * 8;

  f32x4 acc[2][8];
  #pragma unroll
  for (int g = 0; g < 2; ++g)
    #pragma unroll
    for (int u = 0; u < 8; ++u) acc[g][u] = (f32x4){0.f, 0.f, 0.f, 0.f};

  // active slot sets: kc<4 -> {0,1,2,3,4,5} (r,z,i_n); kc>=4 -> {0,1,2,3,6,7} (r,z,h_n)
  bf16x8 bcur[6], bnext[6];
  #pragma unroll
  for (int i = 0; i < 6; ++i) bcur[i] = *(const bf16x8*)(bp + i * 512);

  #pragma unroll
  for (int kc = 0; kc < 8; ++kc) {
    if (kc < 7) {
      #pragma unroll
      for (int i = 0; i < 6; ++i) {
        int us = (kc + 1 < 4) ? i : (i < 4 ? i : i + 2);
        bnext[i] = *(const bf16x8*)(bp + (kc + 1) * 16384 + us * 512);
      }
    }
    bf16x8 a0 = *(const bf16x8*)&Asw[kc * 512 + lane * 8];
    bf16x8 a1 = *(const bf16x8*)&Asw[(8 + kc) * 512 + lane * 8];
    #pragma unroll
    for (int i = 0; i < 6; ++i) {
      int u = (kc < 4) ? i : (i < 4 ? i : i + 2);
      acc[0][u] = __builtin_amdgcn_mfma_f32_16x16x32_bf16(a0, bcur[i], acc[0][u], 0, 0, 0);
      acc[1][u] = __builtin_amdgcn_mfma_f32_16x16x32_bf16(a1, bcur[i], acc[1][u], 0, 0, 0);
    }
    #pragma unroll
    for (int i = 0; i < 6; ++i) bcur[i] = bnext[i];
  }

  // biases: u = gate*2+hu, within-gate col cw = wave*32 + hu*16 + nl
  float bias[8];
  #pragma unroll
  for (int u = 0; u < 8; ++u) {
    int gi = u >> 1, hu = u & 1;
    int cw = wave * 32 + hu * 16 + nl;
    bias[u] = (gi == 0) ? b_ih[cw] + b_hh[cw]
            : (gi == 1) ? b_ih[128 + cw] + b_hh[128 + cw]
            : (gi == 2) ? b_ih[256 + cw]
                        : b_hh[256 + cw];
  }

  // register-resident GRU combine; results -> Osw out-stage
  #pragma unroll
  for (int g = 0; g < 2; ++g) {
    #pragma unroll
    for (int hu = 0; hu < 2; ++hu) {
      int cw = wave * 32 + hu * 16 + nl;     // output column
      int hbase = ((g * 8 + 4 + wave) * 4 + ((hu * 2 + (nl >> 3)) & 3)) * 128 + (nl & 7);
      #pragma unroll
      for (int i = 0; i < 4; ++i) {
        int m = quad * 4 + i;                // row within 16-row group
        float rv = fast_sig(acc[g][0 + hu][i] + bias[0 + hu]);
        float zv = fast_sig(acc[g][2 + hu][i] + bias[2 + hu]);
        float iv = acc[g][4 + hu][i] + bias[4 + hu];
        float hn = acc[g][6 + hu][i] + bias[6 + hu];
        float hv = bf2f(Asw[hbase + m * 8]);
        float n  = fast_tanh(iv + rv * hn);
        float o  = (1.f - zv) * n + zv * hv;
        Osw[(g * 16 + m) * OUT_P + cw] = f2bf(o);
      }
    }
  }
  __syncthreads();

  {  // coalesced store: 32 rows x 128 cols
    int r32 = tid >> 3, c0 = (tid & 7) * 16;
    uint4 v0 = *(const uint4*)&Osw[r32 * OUT_P + c0];
    uint4 v1 = *(const uint4*)&Osw[r32 * OUT_P + c0 + 8];
    uint4* dstp = (uint4*)(h_out + (size_t)(row0 + r32) * 128 + c0);
    dstp[0] = v0;
    dstp[1] = v1;
  }
}

// ---------------- relu + segment mean pool (two-phase, parallel) ----------------
__global__ void k_pool_partial(const u16* __restrict__ h, const int* __restrict__ batch,
                               float* __restrict__ acc) {
  int t = threadIdx.x;  // column 0..127
  int node0 = blockIdx.x * 125;
  int node1 = node0 + 125;
  int cur = batch[node0];
  float sum = 0.f;
  for (int r = node0; r < node1; ++r) {
    int g = batch[r];
    if (g != cur) {
      atomicAdd(&acc[cur * 128 + t], sum);
      sum = 0.f;
      cur = g;
    }
    sum += fmaxf(bf2f(h[(size_t)r * 128 + t]), 0.f);
  }
  atomicAdd(&acc[cur * 128 + t], sum);
}

__global__ void k_pool_div(const float* __restrict__ acc, const int* __restrict__ batch,
                           float* __restrict__ out) {
  __shared__ int se[2];
  int g = blockIdx.x, t = threadIdx.x;
  if (t < 2) {
    int target = g + t;
    int lo = 0, hi = N_NODES;
    while (lo < hi) { int mid = (lo + hi) >> 1; if (batch[mid] < target) lo = mid + 1; else hi = mid; }
    se[t] = lo;
  }
  __syncthreads();
  int cnt = se[1] - se[0];
  out[g * 128 + t] = acc[g * 128 + t] / (float)(cnt > 0 ? cnt : 1);
}

extern "C" void kernel_launch(void* const* d_in, const int* in_sizes, int n_in,
                              void* d_out, int out_size, void* d_ws, size_t ws_size,
                              hipStream_t stream) {
  const float* x     = (const float*)d_in[0];
  const int*   edges = (const int*)d_in[1];
  const int*   batch = (const int*)d_in[2];
  const float* W     = (const float*)d_in[3];
  const float* w_ih  = (const float*)d_in[4];
  const float* w_hh  = (const float*)d_in[5];
  const float* b_ih  = (const float*)d_in[6];
  const float* b_hh  = (const float*)d_in[7];
  float* out = (float*)d_out;

  char* w = (char*)d_ws;
  u16* buf0    = (u16*)(w);                 // 25,600,000 B  (h / s ping)
  u16* buf1    = (u16*)(w + 25600000);      // 25,600,000 B  (h / s pong)
  u16* bsw     = (u16*)(w + 51200000);      // 1,048,576 B
  float* acc   = (float*)(w + 52300032);    // 32,768 B  (pool accumulator)
  int* offs    = (int*)(w + 52710400);      // 400,004 B
  int* gcursor = (int*)(w + 53120768);      // 1,024 B
  int* bcnt    = (int*)(w + 53122048);      // 1,024 B
  int* ebase   = (int*)(w + 53123328);      // 1,028 B
  int* csr     = (int*)(w + 53531136);      // 6,400,000 B  -> total ~60 MB
  u64* ebuf    = (u64*)buf1;                // 12.8 MB; buf1 dead until 1st gather

  const int* esrc = edges;
  const int* edst = edges + N_EDGES;

  hipMemsetAsync(bcnt, 0, NBUCK * sizeof(int), stream);
  k_bhist<<<391, 1024, 0, stream>>>(edst, bcnt);
  k_bscan<<<1, NBUCK, 0, stream>>>(bcnt, ebase, gcursor);
  k_part<<<391, 1024, 0, stream>>>(esrc, edst, gcursor, ebuf);
  k_csr<<<NBUCK, 1024, 0, stream>>>(ebuf, ebase, offs, csr);
  k_wb<<<1024, 128, 0, stream>>>(W, w_ih, w_hh, bsw);
  k_convert<<<(N_NODES * HIDDEN) / 1024, 256, 0, stream>>>(x, buf0);
  hipMemsetAsync(acc, 0, N_GRAPHS * HIDDEN * sizeof(float), stream);

  u16* hcur = buf0;
  u16* hnxt = buf1;
  for (int st = 0; st < STEPS; ++st) {
    k_gather<<<N_NODES / 4, 256, 0, stream>>>(hcur, csr, offs, hnxt);
    // in-place: each block reads only its own 32 rows of s (hnxt) and h (hcur)
    // into LDS before writing h_out (hnxt) over those same rows.
    k_gemm_gru<<<N_NODES / 32, 256, 0, stream>>>(hnxt, hcur, bsw + st * 131072,
                                                 b_ih, b_hh, hnxt);
    u16* tmp = hcur; hcur = hnxt; hnxt = tmp;
  }
  k_pool_partial<<<800, 128, 0, stream>>>(hcur, batch, acc);
  k_pool_div<<<N_GRAPHS, 128, 0, stream>>>(acc, batch, out);
}